// Round 9
// baseline (431.489 us; speedup 1.0000x reference)
//
#include <hip/hip_runtime.h>
#include <math.h>

#define BN_EPS 1e-5f

typedef unsigned short u16;
typedef unsigned int u32;
typedef __attribute__((ext_vector_type(8))) short bf16x8;
typedef __attribute__((ext_vector_type(4))) float f32x4;

__device__ __forceinline__ u16 f2bf(float f) {
  u32 u = __float_as_uint(f);
  u32 r = (u + 0x7fffu + ((u >> 16) & 1u)) >> 16;   // RNE
  return (u16)r;
}
__device__ __forceinline__ u32 packbf2(float x, float y) {
  return (u32)f2bf(x) | ((u32)f2bf(y) << 16);
}
__device__ __forceinline__ float lo_bf(u32 p) { return __uint_as_float(p << 16); }
__device__ __forceinline__ float hi_bf(u32 p) { return __uint_as_float(p & 0xffff0000u); }

__device__ __forceinline__ void unpack4(uint2 p, float* f) {
  f[0] = lo_bf(p.x); f[1] = hi_bf(p.x);
  f[2] = lo_bf(p.y); f[3] = hi_bf(p.y);
}

// ---------------- CSR build ----------------
__global__ __launch_bounds__(256) void count_pos_k(const int* __restrict__ dst,
                                                   int* __restrict__ cnt,
                                                   int* __restrict__ pintra,
                                                   int T, int E) {
  int t = blockIdx.x * 256 + threadIdx.x;
  if (t >= T) return;
  int e0 = t, e1 = t + T, e2 = t + 2 * T, e3 = t + 3 * T;
  int d0 = (e0 < E) ? dst[e0] : -1;
  int d1 = (e1 < E) ? dst[e1] : -1;
  int d2 = (e2 < E) ? dst[e2] : -1;
  int d3 = (e3 < E) ? dst[e3] : -1;
  int p0 = (d0 >= 0) ? atomicAdd(&cnt[d0], 1) : 0;
  int p1 = (d1 >= 0) ? atomicAdd(&cnt[d1], 1) : 0;
  int p2 = (d2 >= 0) ? atomicAdd(&cnt[d2], 1) : 0;
  int p3 = (d3 >= 0) ? atomicAdd(&cnt[d3], 1) : 0;
  if (d0 >= 0) pintra[e0] = p0;
  if (d1 >= 0) pintra[e1] = p1;
  if (d2 >= 0) pintra[e2] = p2;
  if (d3 >= 0) pintra[e3] = p3;
}

__global__ __launch_bounds__(256) void blocksum_k(const int* __restrict__ cnt,
                                                  int* __restrict__ bsum, int n) {
  __shared__ int red[256];
  int tid = threadIdx.x;
  int i = blockIdx.x * 256 + tid;
  int v = (i < n) ? cnt[i] : 0;
  red[tid] = v;
  __syncthreads();
  for (int o = 128; o > 0; o >>= 1) {
    if (tid < o) red[tid] += red[tid + o];
    __syncthreads();
  }
  if (tid == 0) bsum[blockIdx.x] = red[0];
}

__global__ __launch_bounds__(1024) void scan_bsum_k(int* __restrict__ bsum, int nb) {
  __shared__ int part[1024];
  int tid = threadIdx.x;
  int v = (tid < nb) ? bsum[tid] : 0;
  part[tid] = v;
  __syncthreads();
  for (int o = 1; o < 1024; o <<= 1) {
    int t = (tid >= o) ? part[tid - o] : 0;
    __syncthreads();
    part[tid] += t;
    __syncthreads();
  }
  if (tid < nb) bsum[tid] = part[tid] - v;   // exclusive
}

__global__ __launch_bounds__(256) void scan_final_k(const int* __restrict__ cnt,
                                                    const int* __restrict__ bsum,
                                                    int* __restrict__ rowptr,
                                                    float* __restrict__ dinv, int n) {
  __shared__ int part[256];
  int tid = threadIdx.x;
  int i = blockIdx.x * 256 + tid;
  int v = (i < n) ? cnt[i] : 0;
  part[tid] = v;
  __syncthreads();
  for (int o = 1; o < 256; o <<= 1) {
    int t = (tid >= o) ? part[tid - o] : 0;
    __syncthreads();
    part[tid] += t;
    __syncthreads();
  }
  if (i < n) {
    int excl = part[tid] - v + bsum[blockIdx.x];
    rowptr[i] = excl;
    dinv[i] = rsqrtf((float)(v + 1));   // deg = in-degree + self-loop
    if (i == n - 1) rowptr[n] = excl + v;
  }
}

__global__ __launch_bounds__(256) void fill_csr_k(const int* __restrict__ src,
                                                  const int* __restrict__ dst,
                                                  const int* __restrict__ rowptr,
                                                  const int* __restrict__ pintra,
                                                  int2* __restrict__ se, int T, int E) {
  int t = blockIdx.x * 256 + threadIdx.x;
  if (t >= T) return;
  #pragma unroll
  for (int u = 0; u < 4; ++u) {
    int e = t + u * T;
    if (e < E) {
      int d = dst[e];
      int p = rowptr[d] + pintra[e];
      se[p] = make_int2(src[e], e);
    }
  }
}

__global__ __launch_bounds__(256) void split_k(const int2* __restrict__ se,
                                               int* __restrict__ csrS, int E) {
  int t = blockIdx.x * 256 + threadIdx.x;
  if (t < E) csrS[t] = se[t].x;
}

// ---- weight prep: 4 matrices [K=128][N=128] fp32 -> transposed bf16 Wt[n][k] ----
__global__ __launch_bounds__(256) void wconv_k(const float* __restrict__ W1,
    const float* __restrict__ W2, const float* __restrict__ epW1,
    u16* __restrict__ out) {
  int t = blockIdx.x * 256 + threadIdx.x;   // 4 * 16384
  int m = t >> 14, r = t & 16383;
  int n = r >> 7, k = r & 127;
  const float* src = (m == 0) ? W1 : (m == 1) ? W2 : epW1 + (size_t)(m - 2) * 16384;
  out[t] = f2bf(src[k * 128 + n]);
}

// ---- MFMA GEMM: Yblocked[4][M][32] = (X @ W) (+bias) (* dinv[row]) ----
// BLKIN: X in blocked [4][M][32] bf16; else fp32 row-major [M][128].
template<bool BLKIN, bool SCALE, bool BIAS>
__global__ __launch_bounds__(256) void gemm_mfma_k(const void* __restrict__ Xv,
    const u16* __restrict__ Wt, const float* __restrict__ bias,
    const float* __restrict__ dinv, u16* __restrict__ Y, int M) {
  __shared__ u16 Xs[64][136];
  __shared__ u16 Ws[128][136];
  int tid = threadIdx.x;
  int row0 = blockIdx.x * 64;
  for (int i = tid; i < 2048; i += 256) {
    int n = i >> 4, c8 = i & 15;
    uint4 v = ((const uint4*)Wt)[i];
    *(uint4*)&Ws[n][c8 * 8] = v;
  }
  for (int i = tid; i < 1024; i += 256) {
    int r = i >> 4, c8 = i & 15;
    int gr = row0 + r;
    uint4 v = make_uint4(0u, 0u, 0u, 0u);
    if (gr < M) {
      if (BLKIN) {
        const u16* Xb = (const u16*)Xv;
        int q = c8 >> 2, offw = (c8 & 3) * 8;
        v = *(const uint4*)(Xb + (size_t)q * M * 32 + (size_t)gr * 32 + offw);
      } else {
        const float* Xf = (const float*)Xv;
        float4 f0 = ((const float4*)Xf)[(size_t)gr * 32 + c8 * 2];
        float4 f1 = ((const float4*)Xf)[(size_t)gr * 32 + c8 * 2 + 1];
        v.x = packbf2(f0.x, f0.y); v.y = packbf2(f0.z, f0.w);
        v.z = packbf2(f1.x, f1.y); v.w = packbf2(f1.z, f1.w);
      }
    }
    *(uint4*)&Xs[r][c8 * 8] = v;
  }
  __syncthreads();
  int w = tid >> 6, l = tid & 63;
  int lr = l & 15, kq = l >> 4;
  bf16x8 a[4];
  #pragma unroll
  for (int kk = 0; kk < 4; ++kk)
    a[kk] = *(const bf16x8*)&Xs[w * 16 + lr][kk * 32 + kq * 8];
  float sc[4];
  #pragma unroll
  for (int r = 0; r < 4; ++r) {
    int grow = row0 + w * 16 + kq * 4 + r;
    sc[r] = (SCALE && grow < M) ? dinv[grow] : 1.f;
  }
  size_t plane = (size_t)M * 32;
  #pragma unroll
  for (int ct = 0; ct < 8; ++ct) {
    f32x4 c = {0.f, 0.f, 0.f, 0.f};
    #pragma unroll
    for (int kk = 0; kk < 4; ++kk) {
      bf16x8 b = *(const bf16x8*)&Ws[ct * 16 + lr][kk * 32 + kq * 8];
      c = __builtin_amdgcn_mfma_f32_16x16x32_bf16(a[kk], b, c, 0, 0, 0);
    }
    int n = ct * 16 + lr;
    float bv = BIAS ? bias[n] : 0.f;
    size_t sbase = (size_t)(n >> 5) * plane + (n & 31);
    #pragma unroll
    for (int r = 0; r < 4; ++r) {
      int grow = row0 + w * 16 + kq * 4 + r;
      if (grow < M) {
        float o = c[r] + bv;
        if (SCALE) o *= sc[r];
        Y[sbase + (size_t)grow * 32] = f2bf(o);
      }
    }
  }
}

// ---- fused double GEMM (edge predictor): blocked in, blocked out x2 ----
__global__ __launch_bounds__(256) void gemm_mfma2_k(const u16* __restrict__ Xb,
    const u16* __restrict__ WtA, const u16* __restrict__ WtB,
    const float* __restrict__ bias, u16* __restrict__ YA, u16* __restrict__ YB, int M) {
  __shared__ u16 Xs[64][136];
  __shared__ u16 Ws[128][136];
  int tid = threadIdx.x;
  int row0 = blockIdx.x * 64;
  for (int i = tid; i < 1024; i += 256) {
    int r = i >> 4, c8 = i & 15;
    int gr = row0 + r;
    uint4 v = make_uint4(0u, 0u, 0u, 0u);
    if (gr < M) {
      int q = c8 >> 2, offw = (c8 & 3) * 8;
      v = *(const uint4*)(Xb + (size_t)q * M * 32 + (size_t)gr * 32 + offw);
    }
    *(uint4*)&Xs[r][c8 * 8] = v;
  }
  __syncthreads();
  int w = tid >> 6, l = tid & 63;
  int lr = l & 15, kq = l >> 4;
  bf16x8 a[4];
  #pragma unroll
  for (int kk = 0; kk < 4; ++kk)
    a[kk] = *(const bf16x8*)&Xs[w * 16 + lr][kk * 32 + kq * 8];
  size_t plane = (size_t)M * 32;

  for (int m = 0; m < 2; ++m) {
    const u16* Wt = m ? WtB : WtA;
    u16* Y = m ? YB : YA;
    __syncthreads();
    for (int i = tid; i < 2048; i += 256) {
      int n = i >> 4, c8 = i & 15;
      uint4 v = ((const uint4*)Wt)[i];
      *(uint4*)&Ws[n][c8 * 8] = v;
    }
    __syncthreads();
    #pragma unroll
    for (int ct = 0; ct < 8; ++ct) {
      f32x4 c = {0.f, 0.f, 0.f, 0.f};
      #pragma unroll
      for (int kk = 0; kk < 4; ++kk) {
        bf16x8 b = *(const bf16x8*)&Ws[ct * 16 + lr][kk * 32 + kq * 8];
        c = __builtin_amdgcn_mfma_f32_16x16x32_bf16(a[kk], b, c, 0, 0, 0);
      }
      int n = ct * 16 + lr;
      float bv = (m == 0) ? bias[n] : 0.f;
      size_t sbase = (size_t)(n >> 5) * plane + (n & 31);
      #pragma unroll
      for (int r = 0; r < 4; ++r) {
        int grow = row0 + w * 16 + kq * 4 + r;
        if (grow < M) Y[sbase + (size_t)grow * 32] = f2bf(c[r] + bv);
      }
    }
  }
}

// --- agg pass: one 32-channel slice (3.2MB, L2-resident). wave/node, 8 subs x 8 lanes ---
// Xslice rows pre-scaled by dinv[row]; out = BN(relu(dinv[d]*(sum+self)))
__global__ __launch_bounds__(256) void agg_pass_k(const u16* __restrict__ Xslice,
    const int* __restrict__ rowptr, const int* __restrict__ csrS,
    const float* __restrict__ dinv,
    const float* __restrict__ bb, const float* __restrict__ g,
    const float* __restrict__ be, const float* __restrict__ mm,
    const float* __restrict__ vv, int c0,
    u16* __restrict__ Hslice, int n) {
  int node = (blockIdx.x * 256 + threadIdx.x) >> 6;
  if (node >= n) return;
  int lane = threadIdx.x & 63;
  int sub = lane >> 3, l8 = lane & 7;
  int beg = rowptr[node], end = rowptr[node + 1];
  const uint2* X2 = (const uint2*)Xslice;
  float ac[4] = {0.f, 0.f, 0.f, 0.f};
  for (int i = beg + sub; i < end; i += 8) {
    int s = csrS[i];
    float f[4];
    unpack4(X2[(size_t)s * 8 + l8], f);
    ac[0] += f[0]; ac[1] += f[1]; ac[2] += f[2]; ac[3] += f[3];
  }
  #pragma unroll
  for (int j = 0; j < 4; ++j) {
    ac[j] += __shfl_xor(ac[j], 8);
    ac[j] += __shfl_xor(ac[j], 16);
    ac[j] += __shfl_xor(ac[j], 32);
  }
  {
    float f[4];
    unpack4(X2[(size_t)node * 8 + l8], f);
    ac[0] += f[0]; ac[1] += f[1]; ac[2] += f[2]; ac[3] += f[3];
  }
  float dn = dinv[node];
  int c = c0 + l8 * 4;
  float4 gg = *(const float4*)&g[c];
  float4 vv4 = *(const float4*)&vv[c];
  float4 bb4 = *(const float4*)&bb[c];
  float4 mm4 = *(const float4*)&mm[c];
  float4 ee4 = *(const float4*)&be[c];
  float o0 = fmaxf((ac[0] * dn + bb4.x - mm4.x) * (gg.x * rsqrtf(vv4.x + BN_EPS)) + ee4.x, 0.f);
  float o1 = fmaxf((ac[1] * dn + bb4.y - mm4.y) * (gg.y * rsqrtf(vv4.y + BN_EPS)) + ee4.y, 0.f);
  float o2 = fmaxf((ac[2] * dn + bb4.z - mm4.z) * (gg.z * rsqrtf(vv4.z + BN_EPS)) + ee4.z, 0.f);
  float o3 = fmaxf((ac[3] * dn + bb4.w - mm4.w) * (gg.w * rsqrtf(vv4.w + BN_EPS)) + ee4.w, 0.f);
  if (sub == 0) {
    ((uint2*)Hslice)[(size_t)node * 8 + l8] = make_uint2(packbf2(o0, o1), packbf2(o2, o3));
  }
}

// --- edge pass: one 32-channel slice. wave/node, B slice in regs, gather A slice ---
__global__ __launch_bounds__(256) void edge_pass_k(const u16* __restrict__ Aslice,
    const u16* __restrict__ Bslice, const int* __restrict__ rowptr,
    const int* __restrict__ csrS, const float* __restrict__ w2, int c0,
    float* __restrict__ pout, int n) {
  int node = (blockIdx.x * 256 + threadIdx.x) >> 6;
  if (node >= n) return;
  int lane = threadIdx.x & 63;
  int sub = lane >> 3, l8 = lane & 7;
  int beg = rowptr[node], end = rowptr[node + 1];
  if (beg >= end) return;
  const uint2* A2 = (const uint2*)Aslice;
  const uint2* B2 = (const uint2*)Bslice;
  float bv[4];
  unpack4(B2[(size_t)node * 8 + l8], bv);
  float4 wv4 = *(const float4*)&w2[c0 + l8 * 4];
  for (int i = beg + sub; i < end; i += 8) {
    int s = csrS[i];
    float f[4];
    unpack4(A2[(size_t)s * 8 + l8], f);
    float dot;
    dot = fmaxf(f[0] + bv[0], 0.f) * wv4.x;
    dot = fmaf(fmaxf(f[1] + bv[1], 0.f), wv4.y, dot);
    dot = fmaf(fmaxf(f[2] + bv[2], 0.f), wv4.z, dot);
    dot = fmaf(fmaxf(f[3] + bv[3], 0.f), wv4.w, dot);
    dot += __shfl_xor(dot, 1);
    dot += __shfl_xor(dot, 2);
    dot += __shfl_xor(dot, 4);
    if (l8 == 0) pout[i] = dot;
  }
}

// --- finalize: out[eid] = sigmoid(sum of 4 partials + b2) ---
__global__ __launch_bounds__(256) void edge_fin_k(const float* __restrict__ part,
    const int2* __restrict__ se, const float* __restrict__ b2,
    float* __restrict__ out, int E) {
  int t = blockIdx.x * 256 + threadIdx.x;
  if (t >= E) return;
  float z = part[t] + part[(size_t)E + t] + part[2 * (size_t)E + t] +
            part[3 * (size_t)E + t] + b2[0];
  out[se[t].y] = 1.f / (1.f + expf(-z));
}

extern "C" void kernel_launch(void* const* d_in, const int* in_sizes, int n_in,
                              void* d_out, int out_size, void* d_ws, size_t ws_size,
                              hipStream_t stream) {
  const float* x    = (const float*)d_in[0];
  const int*   ei   = (const int*)d_in[1];
  const float* W1   = (const float*)d_in[2];
  const float* b1   = (const float*)d_in[3];
  const float* g1   = (const float*)d_in[4];
  const float* be1  = (const float*)d_in[5];
  const float* m1   = (const float*)d_in[6];
  const float* v1   = (const float*)d_in[7];
  const float* W2   = (const float*)d_in[8];
  const float* b2   = (const float*)d_in[9];
  const float* g2   = (const float*)d_in[10];
  const float* be2  = (const float*)d_in[11];
  const float* m2   = (const float*)d_in[12];
  const float* v2   = (const float*)d_in[13];
  const float* epW1 = (const float*)d_in[14];
  const float* epb1 = (const float*)d_in[15];
  const float* epW2 = (const float*)d_in[16];
  const float* epb2 = (const float*)d_in[17];

  int N = in_sizes[0] / 128;
  int E = in_sizes[1] / 2;
  const int* src = ei;
  const int* dst = ei + E;

  char* w = (char*)d_ws;
  size_t off = 0;
  auto carve = [&](size_t bytes) {
    void* p = w + off;
    off = (off + bytes + 255) & ~(size_t)255;
    return p;
  };
  u16* bufX  = (u16*)carve((size_t)N * 128 * 2);  // blocked: xw' -> t2' -> A
  u16* bufH  = (u16*)carve((size_t)N * 128 * 2);  // blocked: h1 -> h2
  u16* bufB  = (u16*)carve((size_t)N * 128 * 2);  // blocked: B
  int*   cnt   = (int*)carve((size_t)N * 4);
  int*   pintra= (int*)carve((size_t)E * 4);
  int*   rowptr= (int*)carve((size_t)(N + 1) * 4);
  float* dinv  = (float*)carve((size_t)N * 4);
  int2*  se    = (int2*)carve((size_t)E * 8);
  int*   csrS  = (int*)carve((size_t)E * 4);
  int*   bsum  = (int*)carve((size_t)1024 * 4);
  u16*   wsT   = (u16*)carve((size_t)4 * 16384 * 2);
  float* part  = (float*)carve((size_t)4 * E * 4);
  (void)ws_size; (void)n_in; (void)out_size;

  int nb = (N + 255) / 256;
  int T = (E + 3) / 4;
  int tb = (T + 255) / 256;
  size_t plane = (size_t)N * 32;

  hipMemsetAsync(cnt, 0, (size_t)N * 4, stream);
  wconv_k<<<256, 256, 0, stream>>>(W1, W2, epW1, wsT);
  count_pos_k<<<tb, 256, 0, stream>>>(dst, cnt, pintra, T, E);
  blocksum_k<<<nb, 256, 0, stream>>>(cnt, bsum, N);
  scan_bsum_k<<<1, 1024, 0, stream>>>(bsum, nb);
  scan_final_k<<<nb, 256, 0, stream>>>(cnt, bsum, rowptr, dinv, N);
  fill_csr_k<<<tb, 256, 0, stream>>>(src, dst, rowptr, pintra, se, T, E);
  split_k<<<(E + 255) / 256, 256, 0, stream>>>(se, csrS, E);

  int gb = (N + 63) / 64;
  int ab = (N + 3) / 4;   // wave-per-node kernels
  const u16* WtW1 = wsT;
  const u16* WtW2 = wsT + 16384;
  const u16* WtA  = wsT + 2 * 16384;
  const u16* WtB  = wsT + 3 * 16384;

  // layer 1: XW' = dinv * (x @ W1), blocked out
  gemm_mfma_k<false, true, false><<<gb, 256, 0, stream>>>(x, WtW1, nullptr, dinv, bufX, N);
  for (int p = 0; p < 4; ++p)
    agg_pass_k<<<ab, 256, 0, stream>>>(bufX + p * plane, rowptr, csrS, dinv,
                                       b1, g1, be1, m1, v1, p * 32,
                                       bufH + p * plane, N);
  // layer 2
  gemm_mfma_k<true, true, false><<<gb, 256, 0, stream>>>(bufH, WtW2, nullptr, dinv, bufX, N);
  for (int p = 0; p < 4; ++p)
    agg_pass_k<<<ab, 256, 0, stream>>>(bufX + p * plane, rowptr, csrS, dinv,
                                       b2, g2, be2, m2, v2, p * 32,
                                       bufH + p * plane, N);
  // edge predictor GEMMs (fused), blocked outputs
  gemm_mfma2_k<<<gb, 256, 0, stream>>>(bufH, WtA, WtB, epb1, bufX, bufB, N);
  // edge MLP: 4 sequential channel-slice passes + finalize
  for (int p = 0; p < 4; ++p)
    edge_pass_k<<<ab, 256, 0, stream>>>(bufX + p * plane, bufB + p * plane,
                                        rowptr, csrS, epW2, p * 32,
                                        part + (size_t)p * E, N);
  edge_fin_k<<<(E + 255) / 256, 256, 0, stream>>>(part, se, epb2, (float*)d_out, E);
}

// Round 11
// 263.350 us; speedup vs baseline: 1.6385x; 1.6385x over previous
//
#include <hip/hip_runtime.h>
#include <math.h>

#define BN_EPS 1e-5f

typedef unsigned short u16;
typedef unsigned int u32;
typedef unsigned char u8;
typedef __attribute__((ext_vector_type(8))) short bf16x8;
typedef __attribute__((ext_vector_type(4))) float f32x4;

__device__ __forceinline__ u16 f2bf(float f) {
  u32 u = __float_as_uint(f);
  u32 r = (u + 0x7fffu + ((u >> 16) & 1u)) >> 16;   // RNE
  return (u16)r;
}
__device__ __forceinline__ u32 packbf2(float x, float y) {
  return (u32)f2bf(x) | ((u32)f2bf(y) << 16);
}
__device__ __forceinline__ float lo_bf(u32 p) { return __uint_as_float(p << 16); }
__device__ __forceinline__ float hi_bf(u32 p) { return __uint_as_float(p & 0xffff0000u); }

__device__ __forceinline__ void unpack8(uint4 p, float* f) {
  f[0] = lo_bf(p.x); f[1] = hi_bf(p.x);
  f[2] = lo_bf(p.y); f[3] = hi_bf(p.y);
  f[4] = lo_bf(p.z); f[5] = hi_bf(p.z);
  f[6] = lo_bf(p.w); f[7] = hi_bf(p.w);
}

// fp8 e4m3 x4 unpack with literal byte selectors (builtin requires constants)
__device__ __forceinline__ void unpack_fp8x4(u32 p, float* f) {
  f[0] = __builtin_amdgcn_cvt_f32_fp8((int)p, 0);
  f[1] = __builtin_amdgcn_cvt_f32_fp8((int)p, 1);
  f[2] = __builtin_amdgcn_cvt_f32_fp8((int)p, 2);
  f[3] = __builtin_amdgcn_cvt_f32_fp8((int)p, 3);
}

// ---------------- CSR build ----------------
__global__ __launch_bounds__(256) void count_pos_k(const int* __restrict__ dst,
                                                   int* __restrict__ cnt,
                                                   int* __restrict__ pintra,
                                                   int T, int E) {
  int t = blockIdx.x * 256 + threadIdx.x;
  if (t >= T) return;
  int e0 = t, e1 = t + T, e2 = t + 2 * T, e3 = t + 3 * T;
  int d0 = (e0 < E) ? dst[e0] : -1;
  int d1 = (e1 < E) ? dst[e1] : -1;
  int d2 = (e2 < E) ? dst[e2] : -1;
  int d3 = (e3 < E) ? dst[e3] : -1;
  int p0 = (d0 >= 0) ? atomicAdd(&cnt[d0], 1) : 0;
  int p1 = (d1 >= 0) ? atomicAdd(&cnt[d1], 1) : 0;
  int p2 = (d2 >= 0) ? atomicAdd(&cnt[d2], 1) : 0;
  int p3 = (d3 >= 0) ? atomicAdd(&cnt[d3], 1) : 0;
  if (d0 >= 0) pintra[e0] = p0;
  if (d1 >= 0) pintra[e1] = p1;
  if (d2 >= 0) pintra[e2] = p2;
  if (d3 >= 0) pintra[e3] = p3;
}

__global__ __launch_bounds__(256) void blocksum_k(const int* __restrict__ cnt,
                                                  int* __restrict__ bsum, int n) {
  __shared__ int red[256];
  int tid = threadIdx.x;
  int i = blockIdx.x * 256 + tid;
  int v = (i < n) ? cnt[i] : 0;
  red[tid] = v;
  __syncthreads();
  for (int o = 128; o > 0; o >>= 1) {
    if (tid < o) red[tid] += red[tid + o];
    __syncthreads();
  }
  if (tid == 0) bsum[blockIdx.x] = red[0];
}

__global__ __launch_bounds__(1024) void scan_bsum_k(int* __restrict__ bsum, int nb) {
  __shared__ int part[1024];
  int tid = threadIdx.x;
  int v = (tid < nb) ? bsum[tid] : 0;
  part[tid] = v;
  __syncthreads();
  for (int o = 1; o < 1024; o <<= 1) {
    int t = (tid >= o) ? part[tid - o] : 0;
    __syncthreads();
    part[tid] += t;
    __syncthreads();
  }
  if (tid < nb) bsum[tid] = part[tid] - v;   // exclusive
}

__global__ __launch_bounds__(256) void scan_final_k(const int* __restrict__ cnt,
                                                    const int* __restrict__ bsum,
                                                    int* __restrict__ rowptr,
                                                    float* __restrict__ dinv, int n) {
  __shared__ int part[256];
  int tid = threadIdx.x;
  int i = blockIdx.x * 256 + tid;
  int v = (i < n) ? cnt[i] : 0;
  part[tid] = v;
  __syncthreads();
  for (int o = 1; o < 256; o <<= 1) {
    int t = (tid >= o) ? part[tid - o] : 0;
    __syncthreads();
    part[tid] += t;
    __syncthreads();
  }
  if (i < n) {
    int excl = part[tid] - v + bsum[blockIdx.x];
    rowptr[i] = excl;
    dinv[i] = rsqrtf((float)(v + 1));   // deg = in-degree + self-loop
    if (i == n - 1) rowptr[n] = excl + v;
  }
}

// scatter 4B src per edge; eid recoverable as rowptr[dst[e]] + pintra[e]
__global__ __launch_bounds__(256) void fill_csr_k(const int* __restrict__ src,
                                                  const int* __restrict__ dst,
                                                  const int* __restrict__ rowptr,
                                                  const int* __restrict__ pintra,
                                                  int* __restrict__ csrS, int T, int E) {
  int t = blockIdx.x * 256 + threadIdx.x;
  if (t >= T) return;
  #pragma unroll
  for (int u = 0; u < 4; ++u) {
    int e = t + u * T;
    if (e < E) {
      int d = dst[e];
      int p = rowptr[d] + pintra[e];
      csrS[p] = src[e];
    }
  }
}

// ---- weight prep: 4 matrices [K=128][N=128] fp32 -> transposed bf16 Wt[n][k] ----
__global__ __launch_bounds__(256) void wconv_k(const float* __restrict__ W1,
    const float* __restrict__ W2, const float* __restrict__ epW1,
    u16* __restrict__ out) {
  int t = blockIdx.x * 256 + threadIdx.x;   // 4 * 16384
  int m = t >> 14, r = t & 16383;
  int n = r >> 7, k = r & 127;
  const float* src = (m == 0) ? W1 : (m == 1) ? W2 : epW1 + (size_t)(m - 2) * 16384;
  out[t] = f2bf(src[k * 128 + n]);
}

// ---- MFMA GEMM: Y_bf16[M,128] = (X[M,128] @ W) (* dinv[row]) ----
template<bool BF16IN, bool SCALE>
__global__ __launch_bounds__(256) void gemm_mfma_k(const void* __restrict__ Xv,
    const u16* __restrict__ Wt, const float* __restrict__ dinv,
    u16* __restrict__ Y, int M) {
  __shared__ u16 Xs[64][136];
  __shared__ u16 Ws[128][136];
  int tid = threadIdx.x;
  int row0 = blockIdx.x * 64;
  for (int i = tid; i < 2048; i += 256) {
    int n = i >> 4, c8 = i & 15;
    uint4 v = ((const uint4*)Wt)[i];
    *(uint4*)&Ws[n][c8 * 8] = v;
  }
  for (int i = tid; i < 1024; i += 256) {
    int r = i >> 4, c8 = i & 15;
    int gr = row0 + r;
    uint4 v = make_uint4(0u, 0u, 0u, 0u);
    if (gr < M) {
      if (BF16IN) {
        v = ((const uint4*)Xv)[(size_t)gr * 16 + c8];
      } else {
        const float* Xf = (const float*)Xv;
        float4 f0 = ((const float4*)Xf)[(size_t)gr * 32 + c8 * 2];
        float4 f1 = ((const float4*)Xf)[(size_t)gr * 32 + c8 * 2 + 1];
        v.x = packbf2(f0.x, f0.y); v.y = packbf2(f0.z, f0.w);
        v.z = packbf2(f1.x, f1.y); v.w = packbf2(f1.z, f1.w);
      }
    }
    *(uint4*)&Xs[r][c8 * 8] = v;
  }
  __syncthreads();
  int w = tid >> 6, l = tid & 63;
  int lr = l & 15, kq = l >> 4;
  bf16x8 a[4];
  #pragma unroll
  for (int kk = 0; kk < 4; ++kk)
    a[kk] = *(const bf16x8*)&Xs[w * 16 + lr][kk * 32 + kq * 8];
  float sc[4];
  #pragma unroll
  for (int r = 0; r < 4; ++r) {
    int grow = row0 + w * 16 + kq * 4 + r;
    sc[r] = (SCALE && grow < M) ? dinv[grow] : 1.f;
  }
  #pragma unroll
  for (int ct = 0; ct < 8; ++ct) {
    f32x4 c = {0.f, 0.f, 0.f, 0.f};
    #pragma unroll
    for (int kk = 0; kk < 4; ++kk) {
      bf16x8 b = *(const bf16x8*)&Ws[ct * 16 + lr][kk * 32 + kq * 8];
      c = __builtin_amdgcn_mfma_f32_16x16x32_bf16(a[kk], b, c, 0, 0, 0);
    }
    int n = ct * 16 + lr;
    #pragma unroll
    for (int r = 0; r < 4; ++r) {
      int grow = row0 + w * 16 + kq * 4 + r;
      if (grow < M) {
        float o = c[r];
        if (SCALE) o *= sc[r];
        Y[(size_t)grow * 128 + n] = f2bf(o);
      }
    }
  }
}

// ---- fused double GEMM (edge predictor): A out fp8 e4m3 (+bias), B out bf16 ----
__global__ __launch_bounds__(256) void gemm_mfma2_k(const u16* __restrict__ X,
    const u16* __restrict__ WtA, const u16* __restrict__ WtB,
    const float* __restrict__ bias, u8* __restrict__ YA8, u16* __restrict__ YB, int M) {
  __shared__ u16 Xs[64][136];
  __shared__ u16 Ws[128][136];
  int tid = threadIdx.x;
  int row0 = blockIdx.x * 64;
  for (int i = tid; i < 1024; i += 256) {
    int r = i >> 4, c8 = i & 15;
    int gr = row0 + r;
    uint4 v = make_uint4(0u, 0u, 0u, 0u);
    if (gr < M) v = ((const uint4*)X)[(size_t)gr * 16 + c8];
    *(uint4*)&Xs[r][c8 * 8] = v;
  }
  __syncthreads();
  int w = tid >> 6, l = tid & 63;
  int lr = l & 15, kq = l >> 4;
  bf16x8 a[4];
  #pragma unroll
  for (int kk = 0; kk < 4; ++kk)
    a[kk] = *(const bf16x8*)&Xs[w * 16 + lr][kk * 32 + kq * 8];

  for (int m = 0; m < 2; ++m) {
    const u16* Wt = m ? WtB : WtA;
    __syncthreads();
    for (int i = tid; i < 2048; i += 256) {
      int n = i >> 4, c8 = i & 15;
      uint4 v = ((const uint4*)Wt)[i];
      *(uint4*)&Ws[n][c8 * 8] = v;
    }
    __syncthreads();
    #pragma unroll
    for (int ct = 0; ct < 8; ++ct) {
      f32x4 c = {0.f, 0.f, 0.f, 0.f};
      #pragma unroll
      for (int kk = 0; kk < 4; ++kk) {
        bf16x8 b = *(const bf16x8*)&Ws[ct * 16 + lr][kk * 32 + kq * 8];
        c = __builtin_amdgcn_mfma_f32_16x16x32_bf16(a[kk], b, c, 0, 0, 0);
      }
      int n = ct * 16 + lr;
      if (m == 0) {
        float bv = bias[n];
        #pragma unroll
        for (int r = 0; r < 4; ++r) {
          int grow = row0 + w * 16 + kq * 4 + r;
          if (grow < M) {
            float o = c[r] + bv;
            u32 pk = __builtin_amdgcn_cvt_pk_fp8_f32(o, o, 0, false);
            YA8[(size_t)grow * 128 + n] = (u8)(pk & 0xffu);
          }
        }
      } else {
        #pragma unroll
        for (int r = 0; r < 4; ++r) {
          int grow = row0 + w * 16 + kq * 4 + r;
          if (grow < M) YB[(size_t)grow * 128 + n] = f2bf(c[r]);
        }
      }
    }
  }
}

// --- agg: wave per node, 4 edges/iteration (16 lanes x uint4 per row) ---
__global__ __launch_bounds__(256) void agg_bn_relu_k(const uint4* __restrict__ XW4,
    const int* __restrict__ rowptr, const int* __restrict__ csrS,
    const float* __restrict__ dinv,
    const float* __restrict__ bb, const float* __restrict__ g,
    const float* __restrict__ be, const float* __restrict__ mm,
    const float* __restrict__ vv,
    uint4* __restrict__ H4, int n) {
  int node = (blockIdx.x * 256 + threadIdx.x) >> 6;
  if (node >= n) return;
  int lane = threadIdx.x & 63;
  int sub = lane >> 4, l16 = lane & 15;
  int beg = rowptr[node], end = rowptr[node + 1];
  float ac[8];
  #pragma unroll
  for (int j = 0; j < 8; ++j) ac[j] = 0.f;
  for (int i = beg + sub; i < end; i += 4) {
    int s = csrS[i];
    uint4 p = XW4[(size_t)s * 16 + l16];
    float f[8];
    unpack8(p, f);
    #pragma unroll
    for (int j = 0; j < 8; ++j) ac[j] += f[j];
  }
  #pragma unroll
  for (int j = 0; j < 8; ++j) {
    ac[j] += __shfl_xor(ac[j], 16);
    ac[j] += __shfl_xor(ac[j], 32);
  }
  {
    uint4 p = XW4[(size_t)node * 16 + l16];
    float f[8];
    unpack8(p, f);
    #pragma unroll
    for (int j = 0; j < 8; ++j) ac[j] += f[j];
  }
  float dn = dinv[node];
  int c = l16 * 8;
  float4 g0 = *(const float4*)&g[c],  g1 = *(const float4*)&g[c + 4];
  float4 v0 = *(const float4*)&vv[c], v1 = *(const float4*)&vv[c + 4];
  float4 b0 = *(const float4*)&bb[c], b1 = *(const float4*)&bb[c + 4];
  float4 m0 = *(const float4*)&mm[c], m1 = *(const float4*)&mm[c + 4];
  float4 e0 = *(const float4*)&be[c], e1 = *(const float4*)&be[c + 4];
  float gg[8] = {g0.x, g0.y, g0.z, g0.w, g1.x, g1.y, g1.z, g1.w};
  float vvv[8] = {v0.x, v0.y, v0.z, v0.w, v1.x, v1.y, v1.z, v1.w};
  float bbb[8] = {b0.x, b0.y, b0.z, b0.w, b1.x, b1.y, b1.z, b1.w};
  float mmm[8] = {m0.x, m0.y, m0.z, m0.w, m1.x, m1.y, m1.z, m1.w};
  float eee[8] = {e0.x, e0.y, e0.z, e0.w, e1.x, e1.y, e1.z, e1.w};
  u32 out[4];
  #pragma unroll
  for (int j2 = 0; j2 < 4; ++j2) {
    float o0 = (ac[2*j2]   * dn + bbb[2*j2]   - mmm[2*j2])   * (gg[2*j2]   * rsqrtf(vvv[2*j2]   + BN_EPS)) + eee[2*j2];
    float o1 = (ac[2*j2+1] * dn + bbb[2*j2+1] - mmm[2*j2+1]) * (gg[2*j2+1] * rsqrtf(vvv[2*j2+1] + BN_EPS)) + eee[2*j2+1];
    out[j2] = packbf2(fmaxf(o0, 0.f), fmaxf(o1, 0.f));
  }
  if (sub == 0) {
    uint4 pk = make_uint4(out[0], out[1], out[2], out[3]);
    H4[(size_t)node * 16 + l16] = pk;
  }
}

// --- edge pass: node-major; B[d] bf16 in regs; gather A[s] fp8 (1 line/row) ---
// writes partial dot (pre-sigmoid) to pout[csr_pos], coalesced.
__global__ __launch_bounds__(256) void edge_pass_k(const u8* __restrict__ A8,
    const uint4* __restrict__ B4, const int* __restrict__ rowptr,
    const int* __restrict__ csrS, const float* __restrict__ w2,
    float* __restrict__ pout, int n) {
  int node = (blockIdx.x * 256 + threadIdx.x) >> 6;
  if (node >= n) return;
  int lane = threadIdx.x & 63;
  int sub = lane >> 4, l16 = lane & 15;
  int beg = rowptr[node], end = rowptr[node + 1];
  if (beg >= end) return;
  float bvals[8];
  unpack8(B4[(size_t)node * 16 + l16], bvals);
  int c = l16 * 8;
  float4 w0 = *(const float4*)&w2[c];
  float4 w1 = *(const float4*)&w2[c + 4];
  float wv[8] = {w0.x, w0.y, w0.z, w0.w, w1.x, w1.y, w1.z, w1.w};
  const uint2* A2 = (const uint2*)A8;
  for (int i = beg + sub; i < end; i += 4) {
    int s = csrS[i];
    uint2 pa = A2[(size_t)s * 16 + l16];
    float f[8];
    unpack_fp8x4(pa.x, f);
    unpack_fp8x4(pa.y, f + 4);
    float dot = 0.f;
    #pragma unroll
    for (int j = 0; j < 8; ++j)
      dot = fmaf(fmaxf(f[j] + bvals[j], 0.f), wv[j], dot);
    dot += __shfl_xor(dot, 1);
    dot += __shfl_xor(dot, 2);
    dot += __shfl_xor(dot, 4);
    dot += __shfl_xor(dot, 8);
    if (l16 == 0) pout[i] = dot;
  }
}

// --- finalize: out[i] = sigmoid(pout[rowptr[dst[i]] + pintra[i]] + b2) ---
__global__ __launch_bounds__(256) void edge_fin_k(const float* __restrict__ pout,
    const int* __restrict__ dst, const int* __restrict__ pintra,
    const int* __restrict__ rowptr, const float* __restrict__ b2,
    float* __restrict__ out, int E) {
  int t = blockIdx.x * 256 + threadIdx.x;
  if (t >= E) return;
  int p = rowptr[dst[t]] + pintra[t];
  float z = pout[p] + b2[0];
  out[t] = 1.f / (1.f + expf(-z));
}

extern "C" void kernel_launch(void* const* d_in, const int* in_sizes, int n_in,
                              void* d_out, int out_size, void* d_ws, size_t ws_size,
                              hipStream_t stream) {
  const float* x    = (const float*)d_in[0];
  const int*   ei   = (const int*)d_in[1];
  const float* W1   = (const float*)d_in[2];
  const float* b1   = (const float*)d_in[3];
  const float* g1   = (const float*)d_in[4];
  const float* be1  = (const float*)d_in[5];
  const float* m1   = (const float*)d_in[6];
  const float* v1   = (const float*)d_in[7];
  const float* W2   = (const float*)d_in[8];
  const float* b2   = (const float*)d_in[9];
  const float* g2   = (const float*)d_in[10];
  const float* be2  = (const float*)d_in[11];
  const float* m2   = (const float*)d_in[12];
  const float* v2   = (const float*)d_in[13];
  const float* epW1 = (const float*)d_in[14];
  const float* epb1 = (const float*)d_in[15];
  const float* epW2 = (const float*)d_in[16];
  const float* epb2 = (const float*)d_in[17];

  int N = in_sizes[0] / 128;
  int E = in_sizes[1] / 2;
  const int* src = ei;
  const int* dst = ei + E;

  char* w = (char*)d_ws;
  size_t off = 0;
  auto carve = [&](size_t bytes) {
    void* p = w + off;
    off = (off + bytes + 255) & ~(size_t)255;
    return p;
  };
  u16* bufX  = (u16*)carve((size_t)N * 128 * 2);  // xw' -> t2'
  u16* bufH  = (u16*)carve((size_t)N * 128 * 2);  // h1 -> h2
  u16* bufB  = (u16*)carve((size_t)N * 128 * 2);  // B (bf16)
  u8*  bufA8 = (u8*)carve((size_t)N * 128);       // A (fp8 e4m3)
  int*   cnt   = (int*)carve((size_t)N * 4);
  int*   pintra= (int*)carve((size_t)E * 4);
  int*   rowptr= (int*)carve((size_t)(N + 1) * 4);
  float* dinv  = (float*)carve((size_t)N * 4);
  int*   csrS  = (int*)carve((size_t)E * 4);
  int*   bsum  = (int*)carve((size_t)1024 * 4);
  u16*   wsT   = (u16*)carve((size_t)4 * 16384 * 2);
  float* pout  = (float*)carve((size_t)E * 4);
  (void)ws_size; (void)n_in; (void)out_size;

  int nb = (N + 255) / 256;
  int T = (E + 3) / 4;
  int tb = (T + 255) / 256;

  hipMemsetAsync(cnt, 0, (size_t)N * 4, stream);
  wconv_k<<<256, 256, 0, stream>>>(W1, W2, epW1, wsT);
  count_pos_k<<<tb, 256, 0, stream>>>(dst, cnt, pintra, T, E);
  blocksum_k<<<nb, 256, 0, stream>>>(cnt, bsum, N);
  scan_bsum_k<<<1, 1024, 0, stream>>>(bsum, nb);
  scan_final_k<<<nb, 256, 0, stream>>>(cnt, bsum, rowptr, dinv, N);
  fill_csr_k<<<tb, 256, 0, stream>>>(src, dst, rowptr, pintra, csrS, T, E);

  int gb = (N + 63) / 64;
  int ab = (N + 3) / 4;   // wave-per-node kernels
  const u16* WtW1 = wsT;
  const u16* WtW2 = wsT + 16384;
  const u16* WtA  = wsT + 2 * 16384;
  const u16* WtB  = wsT + 3 * 16384;

  // layer 1: XW' = dinv * (x @ W1)
  gemm_mfma_k<false, true><<<gb, 256, 0, stream>>>(x, WtW1, dinv, bufX, N);
  agg_bn_relu_k<<<ab, 256, 0, stream>>>((const uint4*)bufX, rowptr, csrS, dinv,
                                        b1, g1, be1, m1, v1, (uint4*)bufH, N);
  // layer 2
  gemm_mfma_k<true, true><<<gb, 256, 0, stream>>>(bufH, WtW2, dinv, bufX, N);
  agg_bn_relu_k<<<ab, 256, 0, stream>>>((const uint4*)bufX, rowptr, csrS, dinv,
                                        b2, g2, be2, m2, v2, (uint4*)bufH, N);
  // edge predictor: A (fp8, +epb1) and B (bf16), fused
  gemm_mfma2_k<<<gb, 256, 0, stream>>>(bufH, WtA, WtB, epb1, bufA8, bufB, N);
  // edge MLP partial dots (coalesced writes), then finalize with sigmoid
  edge_pass_k<<<ab, 256, 0, stream>>>(bufA8, (const uint4*)bufB, rowptr, csrS,
                                      epW2, pout, N);
  edge_fin_k<<<(E + 255) / 256, 256, 0, stream>>>(pout, dst, pintra, rowptr,
                                                  epb2, (float*)d_out, E);
}

// Round 12
// 249.627 us; speedup vs baseline: 1.7285x; 1.0550x over previous
//
#include <hip/hip_runtime.h>
#include <math.h>

#define BN_EPS 1e-5f

typedef unsigned short u16;
typedef unsigned int u32;
typedef unsigned char u8;
typedef __attribute__((ext_vector_type(8))) short bf16x8;
typedef __attribute__((ext_vector_type(4))) float f32x4;

__device__ __forceinline__ u16 f2bf(float f) {
  u32 u = __float_as_uint(f);
  u32 r = (u + 0x7fffu + ((u >> 16) & 1u)) >> 16;   // RNE
  return (u16)r;
}
__device__ __forceinline__ u32 packbf2(float x, float y) {
  return (u32)f2bf(x) | ((u32)f2bf(y) << 16);
}
__device__ __forceinline__ float lo_bf(u32 p) { return __uint_as_float(p << 16); }
__device__ __forceinline__ float hi_bf(u32 p) { return __uint_as_float(p & 0xffff0000u); }

__device__ __forceinline__ void unpack8(uint4 p, float* f) {
  f[0] = lo_bf(p.x); f[1] = hi_bf(p.x);
  f[2] = lo_bf(p.y); f[3] = hi_bf(p.y);
  f[4] = lo_bf(p.z); f[5] = hi_bf(p.z);
  f[6] = lo_bf(p.w); f[7] = hi_bf(p.w);
}

// fp8 e4m3 x4 unpack with literal byte selectors (builtin requires constants)
__device__ __forceinline__ void unpack_fp8x4(u32 p, float* f) {
  f[0] = __builtin_amdgcn_cvt_f32_fp8((int)p, 0);
  f[1] = __builtin_amdgcn_cvt_f32_fp8((int)p, 1);
  f[2] = __builtin_amdgcn_cvt_f32_fp8((int)p, 2);
  f[3] = __builtin_amdgcn_cvt_f32_fp8((int)p, 3);
}
__device__ __forceinline__ u8 f2fp8(float o) {
  u32 pk = __builtin_amdgcn_cvt_pk_fp8_f32(o, o, 0, false);
  return (u8)(pk & 0xffu);
}

// ---------------- CSR build ----------------
__global__ __launch_bounds__(256) void count_pos_k(const int* __restrict__ dst,
                                                   int* __restrict__ cnt,
                                                   int* __restrict__ pintra,
                                                   int T, int E) {
  int t = blockIdx.x * 256 + threadIdx.x;
  if (t >= T) return;
  int e0 = t, e1 = t + T, e2 = t + 2 * T, e3 = t + 3 * T;
  int d0 = (e0 < E) ? dst[e0] : -1;
  int d1 = (e1 < E) ? dst[e1] : -1;
  int d2 = (e2 < E) ? dst[e2] : -1;
  int d3 = (e3 < E) ? dst[e3] : -1;
  int p0 = (d0 >= 0) ? atomicAdd(&cnt[d0], 1) : 0;
  int p1 = (d1 >= 0) ? atomicAdd(&cnt[d1], 1) : 0;
  int p2 = (d2 >= 0) ? atomicAdd(&cnt[d2], 1) : 0;
  int p3 = (d3 >= 0) ? atomicAdd(&cnt[d3], 1) : 0;
  if (d0 >= 0) pintra[e0] = p0;
  if (d1 >= 0) pintra[e1] = p1;
  if (d2 >= 0) pintra[e2] = p2;
  if (d3 >= 0) pintra[e3] = p3;
}

__global__ __launch_bounds__(256) void blocksum_k(const int* __restrict__ cnt,
                                                  int* __restrict__ bsum, int n) {
  __shared__ int red[256];
  int tid = threadIdx.x;
  int i = blockIdx.x * 256 + tid;
  int v = (i < n) ? cnt[i] : 0;
  red[tid] = v;
  __syncthreads();
  for (int o = 128; o > 0; o >>= 1) {
    if (tid < o) red[tid] += red[tid + o];
    __syncthreads();
  }
  if (tid == 0) bsum[blockIdx.x] = red[0];
}

__global__ __launch_bounds__(1024) void scan_bsum_k(int* __restrict__ bsum, int nb) {
  __shared__ int part[1024];
  int tid = threadIdx.x;
  int v = (tid < nb) ? bsum[tid] : 0;
  part[tid] = v;
  __syncthreads();
  for (int o = 1; o < 1024; o <<= 1) {
    int t = (tid >= o) ? part[tid - o] : 0;
    __syncthreads();
    part[tid] += t;
    __syncthreads();
  }
  if (tid < nb) bsum[tid] = part[tid] - v;   // exclusive
}

__global__ __launch_bounds__(256) void scan_final_k(const int* __restrict__ cnt,
                                                    const int* __restrict__ bsum,
                                                    int* __restrict__ rowptr,
                                                    float* __restrict__ dinv, int n) {
  __shared__ int part[256];
  int tid = threadIdx.x;
  int i = blockIdx.x * 256 + tid;
  int v = (i < n) ? cnt[i] : 0;
  part[tid] = v;
  __syncthreads();
  for (int o = 1; o < 256; o <<= 1) {
    int t = (tid >= o) ? part[tid - o] : 0;
    __syncthreads();
    part[tid] += t;
    __syncthreads();
  }
  if (i < n) {
    int excl = part[tid] - v + bsum[blockIdx.x];
    rowptr[i] = excl;
    dinv[i] = rsqrtf((float)(v + 1));   // deg = in-degree + self-loop
    if (i == n - 1) rowptr[n] = excl + v;
  }
}

// scatter 4B src per edge; eid recoverable as rowptr[dst[e]] + pintra[e]
__global__ __launch_bounds__(256) void fill_csr_k(const int* __restrict__ src,
                                                  const int* __restrict__ dst,
                                                  const int* __restrict__ rowptr,
                                                  const int* __restrict__ pintra,
                                                  int* __restrict__ csrS, int T, int E) {
  int t = blockIdx.x * 256 + threadIdx.x;
  if (t >= T) return;
  #pragma unroll
  for (int u = 0; u < 4; ++u) {
    int e = t + u * T;
    if (e < E) {
      int d = dst[e];
      int p = rowptr[d] + pintra[e];
      csrS[p] = src[e];
    }
  }
}

// ---- weight prep: 4 matrices [K=128][N=128] fp32 -> transposed bf16 Wt[n][k] ----
__global__ __launch_bounds__(256) void wconv_k(const float* __restrict__ W1,
    const float* __restrict__ W2, const float* __restrict__ epW1,
    u16* __restrict__ out) {
  int t = blockIdx.x * 256 + threadIdx.x;   // 4 * 16384
  int m = t >> 14, r = t & 16383;
  int n = r >> 7, k = r & 127;
  const float* src = (m == 0) ? W1 : (m == 1) ? W2 : epW1 + (size_t)(m - 2) * 16384;
  out[t] = f2bf(src[k * 128 + n]);
}

// ---- MFMA GEMM: Y[M,128] = (X[M,128] @ W) (* dinv[row]); out bf16 or fp8 ----
template<bool BF16IN, bool SCALE, bool FP8OUT>
__global__ __launch_bounds__(256) void gemm_mfma_k(const void* __restrict__ Xv,
    const u16* __restrict__ Wt, const float* __restrict__ dinv,
    void* __restrict__ Yv, int M) {
  __shared__ u16 Xs[64][136];
  __shared__ u16 Ws[128][136];
  int tid = threadIdx.x;
  int row0 = blockIdx.x * 64;
  for (int i = tid; i < 2048; i += 256) {
    int n = i >> 4, c8 = i & 15;
    uint4 v = ((const uint4*)Wt)[i];
    *(uint4*)&Ws[n][c8 * 8] = v;
  }
  for (int i = tid; i < 1024; i += 256) {
    int r = i >> 4, c8 = i & 15;
    int gr = row0 + r;
    uint4 v = make_uint4(0u, 0u, 0u, 0u);
    if (gr < M) {
      if (BF16IN) {
        v = ((const uint4*)Xv)[(size_t)gr * 16 + c8];
      } else {
        const float* Xf = (const float*)Xv;
        float4 f0 = ((const float4*)Xf)[(size_t)gr * 32 + c8 * 2];
        float4 f1 = ((const float4*)Xf)[(size_t)gr * 32 + c8 * 2 + 1];
        v.x = packbf2(f0.x, f0.y); v.y = packbf2(f0.z, f0.w);
        v.z = packbf2(f1.x, f1.y); v.w = packbf2(f1.z, f1.w);
      }
    }
    *(uint4*)&Xs[r][c8 * 8] = v;
  }
  __syncthreads();
  int w = tid >> 6, l = tid & 63;
  int lr = l & 15, kq = l >> 4;
  bf16x8 a[4];
  #pragma unroll
  for (int kk = 0; kk < 4; ++kk)
    a[kk] = *(const bf16x8*)&Xs[w * 16 + lr][kk * 32 + kq * 8];
  float sc[4];
  #pragma unroll
  for (int r = 0; r < 4; ++r) {
    int grow = row0 + w * 16 + kq * 4 + r;
    sc[r] = (SCALE && grow < M) ? dinv[grow] : 1.f;
  }
  #pragma unroll
  for (int ct = 0; ct < 8; ++ct) {
    f32x4 c = {0.f, 0.f, 0.f, 0.f};
    #pragma unroll
    for (int kk = 0; kk < 4; ++kk) {
      bf16x8 b = *(const bf16x8*)&Ws[ct * 16 + lr][kk * 32 + kq * 8];
      c = __builtin_amdgcn_mfma_f32_16x16x32_bf16(a[kk], b, c, 0, 0, 0);
    }
    int n = ct * 16 + lr;
    #pragma unroll
    for (int r = 0; r < 4; ++r) {
      int grow = row0 + w * 16 + kq * 4 + r;
      if (grow < M) {
        float o = c[r];
        if (SCALE) o *= sc[r];
        if (FP8OUT) {
          ((u8*)Yv)[(size_t)grow * 128 + n] = f2fp8(o);
        } else {
          ((u16*)Yv)[(size_t)grow * 128 + n] = f2bf(o);
        }
      }
    }
  }
}

// ---- fused double GEMM (edge predictor): A out fp8 e4m3 (+bias), B out bf16 ----
__global__ __launch_bounds__(256) void gemm_mfma2_k(const u16* __restrict__ X,
    const u16* __restrict__ WtA, const u16* __restrict__ WtB,
    const float* __restrict__ bias, u8* __restrict__ YA8, u16* __restrict__ YB, int M) {
  __shared__ u16 Xs[64][136];
  __shared__ u16 Ws[128][136];
  int tid = threadIdx.x;
  int row0 = blockIdx.x * 64;
  for (int i = tid; i < 1024; i += 256) {
    int r = i >> 4, c8 = i & 15;
    int gr = row0 + r;
    uint4 v = make_uint4(0u, 0u, 0u, 0u);
    if (gr < M) v = ((const uint4*)X)[(size_t)gr * 16 + c8];
    *(uint4*)&Xs[r][c8 * 8] = v;
  }
  __syncthreads();
  int w = tid >> 6, l = tid & 63;
  int lr = l & 15, kq = l >> 4;
  bf16x8 a[4];
  #pragma unroll
  for (int kk = 0; kk < 4; ++kk)
    a[kk] = *(const bf16x8*)&Xs[w * 16 + lr][kk * 32 + kq * 8];

  for (int m = 0; m < 2; ++m) {
    const u16* Wt = m ? WtB : WtA;
    __syncthreads();
    for (int i = tid; i < 2048; i += 256) {
      int n = i >> 4, c8 = i & 15;
      uint4 v = ((const uint4*)Wt)[i];
      *(uint4*)&Ws[n][c8 * 8] = v;
    }
    __syncthreads();
    #pragma unroll
    for (int ct = 0; ct < 8; ++ct) {
      f32x4 c = {0.f, 0.f, 0.f, 0.f};
      #pragma unroll
      for (int kk = 0; kk < 4; ++kk) {
        bf16x8 b = *(const bf16x8*)&Ws[ct * 16 + lr][kk * 32 + kq * 8];
        c = __builtin_amdgcn_mfma_f32_16x16x32_bf16(a[kk], b, c, 0, 0, 0);
      }
      int n = ct * 16 + lr;
      if (m == 0) {
        float bv = bias[n];
        #pragma unroll
        for (int r = 0; r < 4; ++r) {
          int grow = row0 + w * 16 + kq * 4 + r;
          if (grow < M) YA8[(size_t)grow * 128 + n] = f2fp8(c[r] + bv);
        }
      } else {
        #pragma unroll
        for (int r = 0; r < 4; ++r) {
          int grow = row0 + w * 16 + kq * 4 + r;
          if (grow < M) YB[(size_t)grow * 128 + n] = f2bf(c[r]);
        }
      }
    }
  }
}

// --- agg: wave per node; XW' fp8 rows (128B, 1 line); 2 gathers/iter (8 in flight) ---
__global__ __launch_bounds__(256) void agg_bn_relu_k(const u8* __restrict__ XW8,
    const int* __restrict__ rowptr, const int* __restrict__ csrS,
    const float* __restrict__ dinv,
    const float* __restrict__ bb, const float* __restrict__ g,
    const float* __restrict__ be, const float* __restrict__ mm,
    const float* __restrict__ vv,
    uint4* __restrict__ H4, int n) {
  int node = (blockIdx.x * 256 + threadIdx.x) >> 6;
  if (node >= n) return;
  int lane = threadIdx.x & 63;
  int sub = lane >> 4, l16 = lane & 15;
  int beg = rowptr[node], end = rowptr[node + 1];
  const uint2* X2 = (const uint2*)XW8;   // row = 16 uint2
  float ac[8];
  #pragma unroll
  for (int j = 0; j < 8; ++j) ac[j] = 0.f;
  for (int i = beg + sub; i < end; i += 8) {
    int s0 = csrS[i];
    uint2 p0 = X2[(size_t)s0 * 16 + l16];
    int i1 = i + 4;
    bool has1 = i1 < end;
    int s1 = has1 ? csrS[i1] : s0;
    uint2 p1 = X2[(size_t)s1 * 16 + l16];
    float f[8];
    unpack_fp8x4(p0.x, f);
    unpack_fp8x4(p0.y, f + 4);
    #pragma unroll
    for (int j = 0; j < 8; ++j) ac[j] += f[j];
    if (has1) {
      unpack_fp8x4(p1.x, f);
      unpack_fp8x4(p1.y, f + 4);
      #pragma unroll
      for (int j = 0; j < 8; ++j) ac[j] += f[j];
    }
  }
  #pragma unroll
  for (int j = 0; j < 8; ++j) {
    ac[j] += __shfl_xor(ac[j], 16);
    ac[j] += __shfl_xor(ac[j], 32);
  }
  {
    uint2 p = X2[(size_t)node * 16 + l16];
    float f[8];
    unpack_fp8x4(p.x, f);
    unpack_fp8x4(p.y, f + 4);
    #pragma unroll
    for (int j = 0; j < 8; ++j) ac[j] += f[j];
  }
  float dn = dinv[node];
  int c = l16 * 8;
  float4 g0 = *(const float4*)&g[c],  g1 = *(const float4*)&g[c + 4];
  float4 v0 = *(const float4*)&vv[c], v1 = *(const float4*)&vv[c + 4];
  float4 b0 = *(const float4*)&bb[c], b1 = *(const float4*)&bb[c + 4];
  float4 m0 = *(const float4*)&mm[c], m1 = *(const float4*)&mm[c + 4];
  float4 e0 = *(const float4*)&be[c], e1 = *(const float4*)&be[c + 4];
  float gg[8] = {g0.x, g0.y, g0.z, g0.w, g1.x, g1.y, g1.z, g1.w};
  float vvv[8] = {v0.x, v0.y, v0.z, v0.w, v1.x, v1.y, v1.z, v1.w};
  float bbb[8] = {b0.x, b0.y, b0.z, b0.w, b1.x, b1.y, b1.z, b1.w};
  float mmm[8] = {m0.x, m0.y, m0.z, m0.w, m1.x, m1.y, m1.z, m1.w};
  float eee[8] = {e0.x, e0.y, e0.z, e0.w, e1.x, e1.y, e1.z, e1.w};
  u32 out[4];
  #pragma unroll
  for (int j2 = 0; j2 < 4; ++j2) {
    float o0 = (ac[2*j2]   * dn + bbb[2*j2]   - mmm[2*j2])   * (gg[2*j2]   * rsqrtf(vvv[2*j2]   + BN_EPS)) + eee[2*j2];
    float o1 = (ac[2*j2+1] * dn + bbb[2*j2+1] - mmm[2*j2+1]) * (gg[2*j2+1] * rsqrtf(vvv[2*j2+1] + BN_EPS)) + eee[2*j2+1];
    out[j2] = packbf2(fmaxf(o0, 0.f), fmaxf(o1, 0.f));
  }
  if (sub == 0) {
    uint4 pk = make_uint4(out[0], out[1], out[2], out[3]);
    H4[(size_t)node * 16 + l16] = pk;
  }
}

// --- edge pass: node-major; B[d] bf16 in regs; gather A[s] fp8; 2 gathers/iter ---
__global__ __launch_bounds__(256) void edge_pass_k(const u8* __restrict__ A8,
    const uint4* __restrict__ B4, const int* __restrict__ rowptr,
    const int* __restrict__ csrS, const float* __restrict__ w2,
    float* __restrict__ pout, int n) {
  int node = (blockIdx.x * 256 + threadIdx.x) >> 6;
  if (node >= n) return;
  int lane = threadIdx.x & 63;
  int sub = lane >> 4, l16 = lane & 15;
  int beg = rowptr[node], end = rowptr[node + 1];
  if (beg >= end) return;
  float bvals[8];
  unpack8(B4[(size_t)node * 16 + l16], bvals);
  int c = l16 * 8;
  float4 w0 = *(const float4*)&w2[c];
  float4 w1 = *(const float4*)&w2[c + 4];
  float wv[8] = {w0.x, w0.y, w0.z, w0.w, w1.x, w1.y, w1.z, w1.w};
  const uint2* A2 = (const uint2*)A8;
  for (int i = beg + sub; i < end; i += 8) {
    int s0 = csrS[i];
    uint2 pa0 = A2[(size_t)s0 * 16 + l16];
    int i1 = i + 4;
    bool has1 = i1 < end;
    int s1 = has1 ? csrS[i1] : s0;
    uint2 pa1 = A2[(size_t)s1 * 16 + l16];
    float f[8];
    unpack_fp8x4(pa0.x, f);
    unpack_fp8x4(pa0.y, f + 4);
    float dot0 = 0.f;
    #pragma unroll
    for (int j = 0; j < 8; ++j)
      dot0 = fmaf(fmaxf(f[j] + bvals[j], 0.f), wv[j], dot0);
    unpack_fp8x4(pa1.x, f);
    unpack_fp8x4(pa1.y, f + 4);
    float dot1 = 0.f;
    #pragma unroll
    for (int j = 0; j < 8; ++j)
      dot1 = fmaf(fmaxf(f[j] + bvals[j], 0.f), wv[j], dot1);
    dot0 += __shfl_xor(dot0, 1);
    dot0 += __shfl_xor(dot0, 2);
    dot0 += __shfl_xor(dot0, 4);
    dot0 += __shfl_xor(dot0, 8);
    dot1 += __shfl_xor(dot1, 1);
    dot1 += __shfl_xor(dot1, 2);
    dot1 += __shfl_xor(dot1, 4);
    dot1 += __shfl_xor(dot1, 8);
    if (l16 == 0) {
      pout[i] = dot0;
      if (has1) pout[i1] = dot1;
    }
  }
}

// --- finalize: out[i] = sigmoid(pout[rowptr[dst[i]] + pintra[i]] + b2) ---
__global__ __launch_bounds__(256) void edge_fin_k(const float* __restrict__ pout,
    const int* __restrict__ dst, const int* __restrict__ pintra,
    const int* __restrict__ rowptr, const float* __restrict__ b2,
    float* __restrict__ out, int E) {
  int t = blockIdx.x * 256 + threadIdx.x;
  if (t >= E) return;
  int p = rowptr[dst[t]] + pintra[t];
  float z = pout[p] + b2[0];
  out[t] = 1.f / (1.f + expf(-z));
}

extern "C" void kernel_launch(void* const* d_in, const int* in_sizes, int n_in,
                              void* d_out, int out_size, void* d_ws, size_t ws_size,
                              hipStream_t stream) {
  const float* x    = (const float*)d_in[0];
  const int*   ei   = (const int*)d_in[1];
  const float* W1   = (const float*)d_in[2];
  const float* b1   = (const float*)d_in[3];
  const float* g1   = (const float*)d_in[4];
  const float* be1  = (const float*)d_in[5];
  const float* m1   = (const float*)d_in[6];
  const float* v1   = (const float*)d_in[7];
  const float* W2   = (const float*)d_in[8];
  const float* b2   = (const float*)d_in[9];
  const float* g2   = (const float*)d_in[10];
  const float* be2  = (const float*)d_in[11];
  const float* m2   = (const float*)d_in[12];
  const float* v2   = (const float*)d_in[13];
  const float* epW1 = (const float*)d_in[14];
  const float* epb1 = (const float*)d_in[15];
  const float* epW2 = (const float*)d_in[16];
  const float* epb2 = (const float*)d_in[17];

  int N = in_sizes[0] / 128;
  int E = in_sizes[1] / 2;
  const int* src = ei;
  const int* dst = ei + E;

  char* w = (char*)d_ws;
  size_t off = 0;
  auto carve = [&](size_t bytes) {
    void* p = w + off;
    off = (off + bytes + 255) & ~(size_t)255;
    return p;
  };
  u8*  bufX8 = (u8*)carve((size_t)N * 128);       // XW' fp8 (layer1/layer2 gathers)
  u16* bufH  = (u16*)carve((size_t)N * 128 * 2);  // h1 -> h2 (bf16)
  u16* bufB  = (u16*)carve((size_t)N * 128 * 2);  // B (bf16)
  u8*  bufA8 = (u8*)carve((size_t)N * 128);       // A (fp8 e4m3)
  int*   cnt   = (int*)carve((size_t)N * 4);
  int*   pintra= (int*)carve((size_t)E * 4);
  int*   rowptr= (int*)carve((size_t)(N + 1) * 4);
  float* dinv  = (float*)carve((size_t)N * 4);
  int*   csrS  = (int*)carve((size_t)E * 4);
  int*   bsum  = (int*)carve((size_t)1024 * 4);
  u16*   wsT   = (u16*)carve((size_t)4 * 16384 * 2);
  float* pout  = (float*)carve((size_t)E * 4);
  (void)ws_size; (void)n_in; (void)out_size;

  int nb = (N + 255) / 256;
  int T = (E + 3) / 4;
  int tb = (T + 255) / 256;

  hipMemsetAsync(cnt, 0, (size_t)N * 4, stream);
  wconv_k<<<256, 256, 0, stream>>>(W1, W2, epW1, wsT);
  count_pos_k<<<tb, 256, 0, stream>>>(dst, cnt, pintra, T, E);
  blocksum_k<<<nb, 256, 0, stream>>>(cnt, bsum, N);
  scan_bsum_k<<<1, 1024, 0, stream>>>(bsum, nb);
  scan_final_k<<<nb, 256, 0, stream>>>(cnt, bsum, rowptr, dinv, N);
  fill_csr_k<<<tb, 256, 0, stream>>>(src, dst, rowptr, pintra, csrS, T, E);

  int gb = (N + 63) / 64;
  int ab = (N + 3) / 4;   // wave-per-node kernels
  const u16* WtW1 = wsT;
  const u16* WtW2 = wsT + 16384;
  const u16* WtA  = wsT + 2 * 16384;
  const u16* WtB  = wsT + 3 * 16384;

  // layer 1: XW' = dinv * (x @ W1) -> fp8
  gemm_mfma_k<false, true, true><<<gb, 256, 0, stream>>>(x, WtW1, dinv, bufX8, N);
  agg_bn_relu_k<<<ab, 256, 0, stream>>>(bufX8, rowptr, csrS, dinv,
                                        b1, g1, be1, m1, v1, (uint4*)bufH, N);
  // layer 2
  gemm_mfma_k<true, true, true><<<gb, 256, 0, stream>>>(bufH, WtW2, dinv, bufX8, N);
  agg_bn_relu_k<<<ab, 256, 0, stream>>>(bufX8, rowptr, csrS, dinv,
                                        b2, g2, be2, m2, v2, (uint4*)bufH, N);
  // edge predictor: A (fp8, +epb1) and B (bf16), fused
  gemm_mfma2_k<<<gb, 256, 0, stream>>>(bufH, WtA, WtB, epb1, bufA8, bufB, N);
  // edge MLP partial dots (coalesced writes), then finalize with sigmoid
  edge_pass_k<<<ab, 256, 0, stream>>>(bufA8, (const uint4*)bufB, rowptr, csrS,
                                      epW2, pout, N);
  edge_fin_k<<<(E + 255) / 256, 256, 0, stream>>>(pout, dst, pintra, rowptr,
                                                  epb2, (float*)d_out, E);
}

// Round 13
// 215.374 us; speedup vs baseline: 2.0034x; 1.1590x over previous
//
#include <hip/hip_runtime.h>
#include <math.h>

#define BN_EPS 1e-5f

typedef unsigned short u16;
typedef unsigned int u32;
typedef unsigned char u8;
typedef __attribute__((ext_vector_type(8))) short bf16x8;
typedef __attribute__((ext_vector_type(4))) float f32x4;

__device__ __forceinline__ u16 f2bf(float f) {
  u32 u = __float_as_uint(f);
  u32 r = (u + 0x7fffu + ((u >> 16) & 1u)) >> 16;   // RNE
  return (u16)r;
}
__device__ __forceinline__ u32 packbf2(float x, float y) {
  return (u32)f2bf(x) | ((u32)f2bf(y) << 16);
}
__device__ __forceinline__ float lo_bf(u32 p) { return __uint_as_float(p << 16); }
__device__ __forceinline__ float hi_bf(u32 p) { return __uint_as_float(p & 0xffff0000u); }

__device__ __forceinline__ void unpack8(uint4 p, float* f) {
  f[0] = lo_bf(p.x); f[1] = hi_bf(p.x);
  f[2] = lo_bf(p.y); f[3] = hi_bf(p.y);
  f[4] = lo_bf(p.z); f[5] = hi_bf(p.z);
  f[6] = lo_bf(p.w); f[7] = hi_bf(p.w);
}

// fp8 e4m3 x4 unpack with literal byte selectors (builtin requires constants)
__device__ __forceinline__ void unpack_fp8x4(u32 p, float* f) {
  f[0] = __builtin_amdgcn_cvt_f32_fp8((int)p, 0);
  f[1] = __builtin_amdgcn_cvt_f32_fp8((int)p, 1);
  f[2] = __builtin_amdgcn_cvt_f32_fp8((int)p, 2);
  f[3] = __builtin_amdgcn_cvt_f32_fp8((int)p, 3);
}
__device__ __forceinline__ u8 f2fp8(float o) {
  u32 pk = __builtin_amdgcn_cvt_pk_fp8_f32(o, o, 0, false);
  return (u8)(pk & 0xffu);
}

// ---------------- CSR build ----------------
__global__ __launch_bounds__(256) void count_pos_k(const int* __restrict__ dst,
                                                   int* __restrict__ cnt,
                                                   int* __restrict__ pintra,
                                                   int T, int E) {
  int t = blockIdx.x * 256 + threadIdx.x;
  if (t >= T) return;
  int e0 = t, e1 = t + T, e2 = t + 2 * T, e3 = t + 3 * T;
  int d0 = (e0 < E) ? dst[e0] : -1;
  int d1 = (e1 < E) ? dst[e1] : -1;
  int d2 = (e2 < E) ? dst[e2] : -1;
  int d3 = (e3 < E) ? dst[e3] : -1;
  int p0 = (d0 >= 0) ? atomicAdd(&cnt[d0], 1) : 0;
  int p1 = (d1 >= 0) ? atomicAdd(&cnt[d1], 1) : 0;
  int p2 = (d2 >= 0) ? atomicAdd(&cnt[d2], 1) : 0;
  int p3 = (d3 >= 0) ? atomicAdd(&cnt[d3], 1) : 0;
  if (d0 >= 0) pintra[e0] = p0;
  if (d1 >= 0) pintra[e1] = p1;
  if (d2 >= 0) pintra[e2] = p2;
  if (d3 >= 0) pintra[e3] = p3;
}

__global__ __launch_bounds__(256) void blocksum_k(const int* __restrict__ cnt,
                                                  int* __restrict__ bsum, int n) {
  __shared__ int red[256];
  int tid = threadIdx.x;
  int i = blockIdx.x * 256 + tid;
  int v = (i < n) ? cnt[i] : 0;
  red[tid] = v;
  __syncthreads();
  for (int o = 128; o > 0; o >>= 1) {
    if (tid < o) red[tid] += red[tid + o];
    __syncthreads();
  }
  if (tid == 0) bsum[blockIdx.x] = red[0];
}

__global__ __launch_bounds__(1024) void scan_bsum_k(int* __restrict__ bsum, int nb) {
  __shared__ int part[1024];
  int tid = threadIdx.x;
  int v = (tid < nb) ? bsum[tid] : 0;
  part[tid] = v;
  __syncthreads();
  for (int o = 1; o < 1024; o <<= 1) {
    int t = (tid >= o) ? part[tid - o] : 0;
    __syncthreads();
    part[tid] += t;
    __syncthreads();
  }
  if (tid < nb) bsum[tid] = part[tid] - v;   // exclusive
}

__global__ __launch_bounds__(256) void scan_final_k(const int* __restrict__ cnt,
                                                    const int* __restrict__ bsum,
                                                    int* __restrict__ rowptr,
                                                    float* __restrict__ dinv, int n) {
  __shared__ int part[256];
  int tid = threadIdx.x;
  int i = blockIdx.x * 256 + tid;
  int v = (i < n) ? cnt[i] : 0;
  part[tid] = v;
  __syncthreads();
  for (int o = 1; o < 256; o <<= 1) {
    int t = (tid >= o) ? part[tid - o] : 0;
    __syncthreads();
    part[tid] += t;
    __syncthreads();
  }
  if (i < n) {
    int excl = part[tid] - v + bsum[blockIdx.x];
    rowptr[i] = excl;
    dinv[i] = rsqrtf((float)(v + 1));   // deg = in-degree + self-loop
    if (i == n - 1) rowptr[n] = excl + v;
  }
}

// scatter 4B src per edge; eid recoverable as rowptr[dst[e]] + pintra[e]
__global__ __launch_bounds__(256) void fill_csr_k(const int* __restrict__ src,
                                                  const int* __restrict__ dst,
                                                  const int* __restrict__ rowptr,
                                                  const int* __restrict__ pintra,
                                                  int* __restrict__ csrS, int T, int E) {
  int t = blockIdx.x * 256 + threadIdx.x;
  if (t >= T) return;
  #pragma unroll
  for (int u = 0; u < 4; ++u) {
    int e = t + u * T;
    if (e < E) {
      int d = dst[e];
      int p = rowptr[d] + pintra[e];
      csrS[p] = src[e];
    }
  }
}

// ---- weight prep: 4 matrices [K=128][N=128] fp32 -> transposed bf16 Wt[n][k] ----
__global__ __launch_bounds__(256) void wconv_k(const float* __restrict__ W1,
    const float* __restrict__ W2, const float* __restrict__ epW1,
    u16* __restrict__ out) {
  int t = blockIdx.x * 256 + threadIdx.x;   // 4 * 16384
  int m = t >> 14, r = t & 16383;
  int n = r >> 7, k = r & 127;
  const float* src = (m == 0) ? W1 : (m == 1) ? W2 : epW1 + (size_t)(m - 2) * 16384;
  out[t] = f2bf(src[k * 128 + n]);
}

// ---- MFMA GEMM: Y[M,128] = (X[M,128] @ W) (* dinv[row]); out bf16 or fp8 ----
template<bool BF16IN, bool SCALE, bool FP8OUT>
__global__ __launch_bounds__(256) void gemm_mfma_k(const void* __restrict__ Xv,
    const u16* __restrict__ Wt, const float* __restrict__ dinv,
    void* __restrict__ Yv, int M) {
  __shared__ u16 Xs[64][136];
  __shared__ u16 Ws[128][136];
  int tid = threadIdx.x;
  int row0 = blockIdx.x * 64;
  for (int i = tid; i < 2048; i += 256) {
    int n = i >> 4, c8 = i & 15;
    uint4 v = ((const uint4*)Wt)[i];
    *(uint4*)&Ws[n][c8 * 8] = v;
  }
  for (int i = tid; i < 1024; i += 256) {
    int r = i >> 4, c8 = i & 15;
    int gr = row0 + r;
    uint4 v = make_uint4(0u, 0u, 0u, 0u);
    if (gr < M) {
      if (BF16IN) {
        v = ((const uint4*)Xv)[(size_t)gr * 16 + c8];
      } else {
        const float* Xf = (const float*)Xv;
        float4 f0 = ((const float4*)Xf)[(size_t)gr * 32 + c8 * 2];
        float4 f1 = ((const float4*)Xf)[(size_t)gr * 32 + c8 * 2 + 1];
        v.x = packbf2(f0.x, f0.y); v.y = packbf2(f0.z, f0.w);
        v.z = packbf2(f1.x, f1.y); v.w = packbf2(f1.z, f1.w);
      }
    }
    *(uint4*)&Xs[r][c8 * 8] = v;
  }
  __syncthreads();
  int w = tid >> 6, l = tid & 63;
  int lr = l & 15, kq = l >> 4;
  bf16x8 a[4];
  #pragma unroll
  for (int kk = 0; kk < 4; ++kk)
    a[kk] = *(const bf16x8*)&Xs[w * 16 + lr][kk * 32 + kq * 8];
  float sc[4];
  #pragma unroll
  for (int r = 0; r < 4; ++r) {
    int grow = row0 + w * 16 + kq * 4 + r;
    sc[r] = (SCALE && grow < M) ? dinv[grow] : 1.f;
  }
  #pragma unroll
  for (int ct = 0; ct < 8; ++ct) {
    f32x4 c = {0.f, 0.f, 0.f, 0.f};
    #pragma unroll
    for (int kk = 0; kk < 4; ++kk) {
      bf16x8 b = *(const bf16x8*)&Ws[ct * 16 + lr][kk * 32 + kq * 8];
      c = __builtin_amdgcn_mfma_f32_16x16x32_bf16(a[kk], b, c, 0, 0, 0);
    }
    int n = ct * 16 + lr;
    #pragma unroll
    for (int r = 0; r < 4; ++r) {
      int grow = row0 + w * 16 + kq * 4 + r;
      if (grow < M) {
        float o = c[r];
        if (SCALE) o *= sc[r];
        if (FP8OUT) {
          ((u8*)Yv)[(size_t)grow * 128 + n] = f2fp8(o);
        } else {
          ((u16*)Yv)[(size_t)grow * 128 + n] = f2bf(o);
        }
      }
    }
  }
}

// ---- fused double GEMM (edge predictor): A out fp8 e4m3 (+bias), B out bf16 ----
__global__ __launch_bounds__(256) void gemm_mfma2_k(const u16* __restrict__ X,
    const u16* __restrict__ WtA, const u16* __restrict__ WtB,
    const float* __restrict__ bias, u8* __restrict__ YA8, u16* __restrict__ YB, int M) {
  __shared__ u16 Xs[64][136];
  __shared__ u16 Ws[128][136];
  int tid = threadIdx.x;
  int row0 = blockIdx.x * 64;
  for (int i = tid; i < 1024; i += 256) {
    int r = i >> 4, c8 = i & 15;
    int gr = row0 + r;
    uint4 v = make_uint4(0u, 0u, 0u, 0u);
    if (gr < M) v = ((const uint4*)X)[(size_t)gr * 16 + c8];
    *(uint4*)&Xs[r][c8 * 8] = v;
  }
  __syncthreads();
  int w = tid >> 6, l = tid & 63;
  int lr = l & 15, kq = l >> 4;
  bf16x8 a[4];
  #pragma unroll
  for (int kk = 0; kk < 4; ++kk)
    a[kk] = *(const bf16x8*)&Xs[w * 16 + lr][kk * 32 + kq * 8];

  for (int m = 0; m < 2; ++m) {
    const u16* Wt = m ? WtB : WtA;
    __syncthreads();
    for (int i = tid; i < 2048; i += 256) {
      int n = i >> 4, c8 = i & 15;
      uint4 v = ((const uint4*)Wt)[i];
      *(uint4*)&Ws[n][c8 * 8] = v;
    }
    __syncthreads();
    #pragma unroll
    for (int ct = 0; ct < 8; ++ct) {
      f32x4 c = {0.f, 0.f, 0.f, 0.f};
      #pragma unroll
      for (int kk = 0; kk < 4; ++kk) {
        bf16x8 b = *(const bf16x8*)&Ws[ct * 16 + lr][kk * 32 + kq * 8];
        c = __builtin_amdgcn_mfma_f32_16x16x32_bf16(a[kk], b, c, 0, 0, 0);
      }
      int n = ct * 16 + lr;
      if (m == 0) {
        float bv = bias[n];
        #pragma unroll
        for (int r = 0; r < 4; ++r) {
          int grow = row0 + w * 16 + kq * 4 + r;
          if (grow < M) YA8[(size_t)grow * 128 + n] = f2fp8(c[r] + bv);
        }
      } else {
        #pragma unroll
        for (int r = 0; r < 4; ++r) {
          int grow = row0 + w * 16 + kq * 4 + r;
          if (grow < M) YB[(size_t)grow * 128 + n] = f2bf(c[r]);
        }
      }
    }
  }
}

// --- agg: 16 lanes per node (4 nodes/wave); NO cross-lane reduce; 4 loads in flight ---
__global__ __launch_bounds__(256) void agg_bn_relu_k(const u8* __restrict__ XW8,
    const int* __restrict__ rowptr, const int* __restrict__ csrS,
    const float* __restrict__ dinv,
    const float* __restrict__ bb, const float* __restrict__ g,
    const float* __restrict__ be, const float* __restrict__ mm,
    const float* __restrict__ vv,
    uint4* __restrict__ H4, int n) {
  int node = (blockIdx.x * 256 + threadIdx.x) >> 4;
  if (node >= n) return;
  int l16 = threadIdx.x & 15;
  int beg = rowptr[node], end = rowptr[node + 1];
  const uint2* X2 = (const uint2*)XW8;   // row = 16 uint2 (128B)
  float ac[8];
  #pragma unroll
  for (int j = 0; j < 8; ++j) ac[j] = 0.f;
  float f[8];
  int i = beg;
  for (; i + 3 < end; i += 4) {
    int s0 = csrS[i];
    int s1 = csrS[i + 1];
    int s2 = csrS[i + 2];
    int s3 = csrS[i + 3];
    uint2 p0 = X2[(size_t)s0 * 16 + l16];
    uint2 p1 = X2[(size_t)s1 * 16 + l16];
    uint2 p2 = X2[(size_t)s2 * 16 + l16];
    uint2 p3 = X2[(size_t)s3 * 16 + l16];
    unpack_fp8x4(p0.x, f); unpack_fp8x4(p0.y, f + 4);
    #pragma unroll
    for (int j = 0; j < 8; ++j) ac[j] += f[j];
    unpack_fp8x4(p1.x, f); unpack_fp8x4(p1.y, f + 4);
    #pragma unroll
    for (int j = 0; j < 8; ++j) ac[j] += f[j];
    unpack_fp8x4(p2.x, f); unpack_fp8x4(p2.y, f + 4);
    #pragma unroll
    for (int j = 0; j < 8; ++j) ac[j] += f[j];
    unpack_fp8x4(p3.x, f); unpack_fp8x4(p3.y, f + 4);
    #pragma unroll
    for (int j = 0; j < 8; ++j) ac[j] += f[j];
  }
  for (; i < end; ++i) {
    uint2 p = X2[(size_t)csrS[i] * 16 + l16];
    unpack_fp8x4(p.x, f); unpack_fp8x4(p.y, f + 4);
    #pragma unroll
    for (int j = 0; j < 8; ++j) ac[j] += f[j];
  }
  {
    uint2 p = X2[(size_t)node * 16 + l16];
    unpack_fp8x4(p.x, f); unpack_fp8x4(p.y, f + 4);
    #pragma unroll
    for (int j = 0; j < 8; ++j) ac[j] += f[j];
  }
  float dn = dinv[node];
  int c = l16 * 8;
  float4 g0 = *(const float4*)&g[c],  g1 = *(const float4*)&g[c + 4];
  float4 v0 = *(const float4*)&vv[c], v1 = *(const float4*)&vv[c + 4];
  float4 b0 = *(const float4*)&bb[c], b1 = *(const float4*)&bb[c + 4];
  float4 m0 = *(const float4*)&mm[c], m1 = *(const float4*)&mm[c + 4];
  float4 e0 = *(const float4*)&be[c], e1 = *(const float4*)&be[c + 4];
  float gg[8] = {g0.x, g0.y, g0.z, g0.w, g1.x, g1.y, g1.z, g1.w};
  float vvv[8] = {v0.x, v0.y, v0.z, v0.w, v1.x, v1.y, v1.z, v1.w};
  float bbb[8] = {b0.x, b0.y, b0.z, b0.w, b1.x, b1.y, b1.z, b1.w};
  float mmm[8] = {m0.x, m0.y, m0.z, m0.w, m1.x, m1.y, m1.z, m1.w};
  float eee[8] = {e0.x, e0.y, e0.z, e0.w, e1.x, e1.y, e1.z, e1.w};
  u32 out[4];
  #pragma unroll
  for (int j2 = 0; j2 < 4; ++j2) {
    float o0 = (ac[2*j2]   * dn + bbb[2*j2]   - mmm[2*j2])   * (gg[2*j2]   * rsqrtf(vvv[2*j2]   + BN_EPS)) + eee[2*j2];
    float o1 = (ac[2*j2+1] * dn + bbb[2*j2+1] - mmm[2*j2+1]) * (gg[2*j2+1] * rsqrtf(vvv[2*j2+1] + BN_EPS)) + eee[2*j2+1];
    out[j2] = packbf2(fmaxf(o0, 0.f), fmaxf(o1, 0.f));
  }
  H4[(size_t)node * 16 + l16] = make_uint4(out[0], out[1], out[2], out[3]);
}

// --- edge pass: node-major; B[d] bf16 in regs; gather A[s] fp8; 4 loads in flight ---
__global__ __launch_bounds__(256) void edge_pass_k(const u8* __restrict__ A8,
    const uint4* __restrict__ B4, const int* __restrict__ rowptr,
    const int* __restrict__ csrS, const float* __restrict__ w2,
    float* __restrict__ pout, int n) {
  int node = (blockIdx.x * 256 + threadIdx.x) >> 6;
  if (node >= n) return;
  int lane = threadIdx.x & 63;
  int sub = lane >> 4, l16 = lane & 15;
  int beg = rowptr[node], end = rowptr[node + 1];
  if (beg >= end) return;
  float bvals[8];
  unpack8(B4[(size_t)node * 16 + l16], bvals);
  int c = l16 * 8;
  float4 w0 = *(const float4*)&w2[c];
  float4 w1 = *(const float4*)&w2[c + 4];
  float wv[8] = {w0.x, w0.y, w0.z, w0.w, w1.x, w1.y, w1.z, w1.w};
  const uint2* A2 = (const uint2*)A8;
  for (int i = beg + sub; i < end; i += 16) {
    int i1 = i + 4, i2 = i + 8, i3 = i + 12;
    bool h1 = i1 < end, h2 = i2 < end, h3 = i3 < end;
    int s0 = csrS[i];
    int s1 = h1 ? csrS[i1] : s0;
    int s2 = h2 ? csrS[i2] : s0;
    int s3 = h3 ? csrS[i3] : s0;
    uint2 pa0 = A2[(size_t)s0 * 16 + l16];
    uint2 pa1 = A2[(size_t)s1 * 16 + l16];
    uint2 pa2 = A2[(size_t)s2 * 16 + l16];
    uint2 pa3 = A2[(size_t)s3 * 16 + l16];
    float f[8];
    float dot0 = 0.f, dot1 = 0.f, dot2 = 0.f, dot3 = 0.f;
    unpack_fp8x4(pa0.x, f); unpack_fp8x4(pa0.y, f + 4);
    #pragma unroll
    for (int j = 0; j < 8; ++j) dot0 = fmaf(fmaxf(f[j] + bvals[j], 0.f), wv[j], dot0);
    unpack_fp8x4(pa1.x, f); unpack_fp8x4(pa1.y, f + 4);
    #pragma unroll
    for (int j = 0; j < 8; ++j) dot1 = fmaf(fmaxf(f[j] + bvals[j], 0.f), wv[j], dot1);
    unpack_fp8x4(pa2.x, f); unpack_fp8x4(pa2.y, f + 4);
    #pragma unroll
    for (int j = 0; j < 8; ++j) dot2 = fmaf(fmaxf(f[j] + bvals[j], 0.f), wv[j], dot2);
    unpack_fp8x4(pa3.x, f); unpack_fp8x4(pa3.y, f + 4);
    #pragma unroll
    for (int j = 0; j < 8; ++j) dot3 = fmaf(fmaxf(f[j] + bvals[j], 0.f), wv[j], dot3);
    #pragma unroll
    for (int o = 1; o <= 8; o <<= 1) {
      dot0 += __shfl_xor(dot0, o);
      dot1 += __shfl_xor(dot1, o);
      dot2 += __shfl_xor(dot2, o);
      dot3 += __shfl_xor(dot3, o);
    }
    if (l16 == 0) {
      pout[i] = dot0;
      if (h1) pout[i1] = dot1;
      if (h2) pout[i2] = dot2;
      if (h3) pout[i3] = dot3;
    }
  }
}

// --- finalize: out[i] = sigmoid(pout[rowptr[dst[i]] + pintra[i]] + b2) ---
__global__ __launch_bounds__(256) void edge_fin_k(const float* __restrict__ pout,
    const int* __restrict__ dst, const int* __restrict__ pintra,
    const int* __restrict__ rowptr, const float* __restrict__ b2,
    float* __restrict__ out, int E) {
  int t = blockIdx.x * 256 + threadIdx.x;
  if (t >= E) return;
  int p = rowptr[dst[t]] + pintra[t];
  float z = pout[p] + b2[0];
  out[t] = 1.f / (1.f + expf(-z));
}

extern "C" void kernel_launch(void* const* d_in, const int* in_sizes, int n_in,
                              void* d_out, int out_size, void* d_ws, size_t ws_size,
                              hipStream_t stream) {
  const float* x    = (const float*)d_in[0];
  const int*   ei   = (const int*)d_in[1];
  const float* W1   = (const float*)d_in[2];
  const float* b1   = (const float*)d_in[3];
  const float* g1   = (const float*)d_in[4];
  const float* be1  = (const float*)d_in[5];
  const float* m1   = (const float*)d_in[6];
  const float* v1   = (const float*)d_in[7];
  const float* W2   = (const float*)d_in[8];
  const float* b2   = (const float*)d_in[9];
  const float* g2   = (const float*)d_in[10];
  const float* be2  = (const float*)d_in[11];
  const float* m2   = (const float*)d_in[12];
  const float* v2   = (const float*)d_in[13];
  const float* epW1 = (const float*)d_in[14];
  const float* epb1 = (const float*)d_in[15];
  const float* epW2 = (const float*)d_in[16];
  const float* epb2 = (const float*)d_in[17];

  int N = in_sizes[0] / 128;
  int E = in_sizes[1] / 2;
  const int* src = ei;
  const int* dst = ei + E;

  char* w = (char*)d_ws;
  size_t off = 0;
  auto carve = [&](size_t bytes) {
    void* p = w + off;
    off = (off + bytes + 255) & ~(size_t)255;
    return p;
  };
  u8*  bufX8 = (u8*)carve((size_t)N * 128);       // XW' fp8 (layer1/layer2 gathers)
  u16* bufH  = (u16*)carve((size_t)N * 128 * 2);  // h1 -> h2 (bf16)
  u16* bufB  = (u16*)carve((size_t)N * 128 * 2);  // B (bf16)
  u8*  bufA8 = (u8*)carve((size_t)N * 128);       // A (fp8 e4m3)
  int*   cnt   = (int*)carve((size_t)N * 4);
  int*   pintra= (int*)carve((size_t)E * 4);
  int*   rowptr= (int*)carve((size_t)(N + 1) * 4);
  float* dinv  = (float*)carve((size_t)N * 4);
  int*   csrS  = (int*)carve((size_t)E * 4);
  int*   bsum  = (int*)carve((size_t)1024 * 4);
  u16*   wsT   = (u16*)carve((size_t)4 * 16384 * 2);
  float* pout  = (float*)carve((size_t)E * 4);
  (void)ws_size; (void)n_in; (void)out_size;

  int nb = (N + 255) / 256;
  int T = (E + 3) / 4;
  int tb = (T + 255) / 256;

  hipMemsetAsync(cnt, 0, (size_t)N * 4, stream);
  wconv_k<<<256, 256, 0, stream>>>(W1, W2, epW1, wsT);
  count_pos_k<<<tb, 256, 0, stream>>>(dst, cnt, pintra, T, E);
  blocksum_k<<<nb, 256, 0, stream>>>(cnt, bsum, N);
  scan_bsum_k<<<1, 1024, 0, stream>>>(bsum, nb);
  scan_final_k<<<nb, 256, 0, stream>>>(cnt, bsum, rowptr, dinv, N);
  fill_csr_k<<<tb, 256, 0, stream>>>(src, dst, rowptr, pintra, csrS, T, E);

  int gb = (N + 63) / 64;
  int an = (N + 15) / 16;   // agg: 16 nodes per block (16 lanes/node)
  int ab = (N + 3) / 4;     // edge pass: wave per node
  const u16* WtW1 = wsT;
  const u16* WtW2 = wsT + 16384;
  const u16* WtA  = wsT + 2 * 16384;
  const u16* WtB  = wsT + 3 * 16384;

  // layer 1: XW' = dinv * (x @ W1) -> fp8
  gemm_mfma_k<false, true, true><<<gb, 256, 0, stream>>>(x, WtW1, dinv, bufX8, N);
  agg_bn_relu_k<<<an, 256, 0, stream>>>(bufX8, rowptr, csrS, dinv,
                                        b1, g1, be1, m1, v1, (uint4*)bufH, N);
  // layer 2
  gemm_mfma_k<true, true, true><<<gb, 256, 0, stream>>>(bufH, WtW2, dinv, bufX8, N);
  agg_bn_relu_k<<<an, 256, 0, stream>>>(bufX8, rowptr, csrS, dinv,
                                        b2, g2, be2, m2, v2, (uint4*)bufH, N);
  // edge predictor: A (fp8, +epb1) and B (bf16), fused
  gemm_mfma2_k<<<gb, 256, 0, stream>>>(bufH, WtA, WtB, epb1, bufA8, bufB, N);
  // edge MLP partial dots (coalesced writes), then finalize with sigmoid
  edge_pass_k<<<ab, 256, 0, stream>>>(bufA8, (const uint4*)bufB, rowptr, csrS,
                                      epW2, pout, N);
  edge_fin_k<<<(E + 255) / 256, 256, 0, stream>>>(pout, dst, pintra, rowptr,
                                                  epb2, (float*)d_out, E);
}

// Round 14
// 213.711 us; speedup vs baseline: 2.0190x; 1.0078x over previous
//
#include <hip/hip_runtime.h>
#include <math.h>

#define BN_EPS 1e-5f

typedef unsigned short u16;
typedef unsigned int u32;
typedef unsigned char u8;
typedef __attribute__((ext_vector_type(8))) short bf16x8;
typedef __attribute__((ext_vector_type(4))) float f32x4;

__device__ __forceinline__ u16 f2bf(float f) {
  u32 u = __float_as_uint(f);
  u32 r = (u + 0x7fffu + ((u >> 16) & 1u)) >> 16;   // RNE
  return (u16)r;
}
__device__ __forceinline__ u32 packbf2(float x, float y) {
  return (u32)f2bf(x) | ((u32)f2bf(y) << 16);
}
__device__ __forceinline__ float lo_bf(u32 p) { return __uint_as_float(p << 16); }
__device__ __forceinline__ float hi_bf(u32 p) { return __uint_as_float(p & 0xffff0000u); }

__device__ __forceinline__ void unpack8(uint4 p, float* f) {
  f[0] = lo_bf(p.x); f[1] = hi_bf(p.x);
  f[2] = lo_bf(p.y); f[3] = hi_bf(p.y);
  f[4] = lo_bf(p.z); f[5] = hi_bf(p.z);
  f[6] = lo_bf(p.w); f[7] = hi_bf(p.w);
}

// fp8 e4m3 x4 unpack with literal byte selectors (builtin requires constants)
__device__ __forceinline__ void unpack_fp8x4(u32 p, float* f) {
  f[0] = __builtin_amdgcn_cvt_f32_fp8((int)p, 0);
  f[1] = __builtin_amdgcn_cvt_f32_fp8((int)p, 1);
  f[2] = __builtin_amdgcn_cvt_f32_fp8((int)p, 2);
  f[3] = __builtin_amdgcn_cvt_f32_fp8((int)p, 3);
}
__device__ __forceinline__ u8 f2fp8(float o) {
  u32 pk = __builtin_amdgcn_cvt_pk_fp8_f32(o, o, 0, false);
  return (u8)(pk & 0xffu);
}

// ---------------- CSR build ----------------
__global__ __launch_bounds__(256) void count_pos_k(const int* __restrict__ dst,
                                                   int* __restrict__ cnt,
                                                   int* __restrict__ pintra,
                                                   int T, int E) {
  int t = blockIdx.x * 256 + threadIdx.x;
  if (t >= T) return;
  int e0 = t, e1 = t + T, e2 = t + 2 * T, e3 = t + 3 * T;
  int d0 = (e0 < E) ? dst[e0] : -1;
  int d1 = (e1 < E) ? dst[e1] : -1;
  int d2 = (e2 < E) ? dst[e2] : -1;
  int d3 = (e3 < E) ? dst[e3] : -1;
  int p0 = (d0 >= 0) ? atomicAdd(&cnt[d0], 1) : 0;
  int p1 = (d1 >= 0) ? atomicAdd(&cnt[d1], 1) : 0;
  int p2 = (d2 >= 0) ? atomicAdd(&cnt[d2], 1) : 0;
  int p3 = (d3 >= 0) ? atomicAdd(&cnt[d3], 1) : 0;
  if (d0 >= 0) pintra[e0] = p0;
  if (d1 >= 0) pintra[e1] = p1;
  if (d2 >= 0) pintra[e2] = p2;
  if (d3 >= 0) pintra[e3] = p3;
}

__global__ __launch_bounds__(256) void blocksum_k(const int* __restrict__ cnt,
                                                  int* __restrict__ bsum, int n) {
  __shared__ int red[256];
  int tid = threadIdx.x;
  int i = blockIdx.x * 256 + tid;
  int v = (i < n) ? cnt[i] : 0;
  red[tid] = v;
  __syncthreads();
  for (int o = 128; o > 0; o >>= 1) {
    if (tid < o) red[tid] += red[tid + o];
    __syncthreads();
  }
  if (tid == 0) bsum[blockIdx.x] = red[0];
}

__global__ __launch_bounds__(1024) void scan_bsum_k(int* __restrict__ bsum, int nb) {
  __shared__ int part[1024];
  int tid = threadIdx.x;
  int v = (tid < nb) ? bsum[tid] : 0;
  part[tid] = v;
  __syncthreads();
  for (int o = 1; o < 1024; o <<= 1) {
    int t = (tid >= o) ? part[tid - o] : 0;
    __syncthreads();
    part[tid] += t;
    __syncthreads();
  }
  if (tid < nb) bsum[tid] = part[tid] - v;   // exclusive
}

__global__ __launch_bounds__(256) void scan_final_k(const int* __restrict__ cnt,
                                                    const int* __restrict__ bsum,
                                                    int* __restrict__ rowptr,
                                                    float* __restrict__ dinv, int n) {
  __shared__ int part[256];
  int tid = threadIdx.x;
  int i = blockIdx.x * 256 + tid;
  int v = (i < n) ? cnt[i] : 0;
  part[tid] = v;
  __syncthreads();
  for (int o = 1; o < 256; o <<= 1) {
    int t = (tid >= o) ? part[tid - o] : 0;
    __syncthreads();
    part[tid] += t;
    __syncthreads();
  }
  if (i < n) {
    int excl = part[tid] - v + bsum[blockIdx.x];
    rowptr[i] = excl;
    dinv[i] = rsqrtf((float)(v + 1));   // deg = in-degree + self-loop
    if (i == n - 1) rowptr[n] = excl + v;
  }
}

// scatter 4B src per edge; eid recoverable as rowptr[dst[e]] + pintra[e]
__global__ __launch_bounds__(256) void fill_csr_k(const int* __restrict__ src,
                                                  const int* __restrict__ dst,
                                                  const int* __restrict__ rowptr,
                                                  const int* __restrict__ pintra,
                                                  int* __restrict__ csrS, int T, int E) {
  int t = blockIdx.x * 256 + threadIdx.x;
  if (t >= T) return;
  #pragma unroll
  for (int u = 0; u < 4; ++u) {
    int e = t + u * T;
    if (e < E) {
      int d = dst[e];
      int p = rowptr[d] + pintra[e];
      csrS[p] = src[e];
    }
  }
}

// ---- weight prep: 4 matrices [K=128][N=128] fp32 -> transposed bf16 Wt[n][k] ----
__global__ __launch_bounds__(256) void wconv_k(const float* __restrict__ W1,
    const float* __restrict__ W2, const float* __restrict__ epW1,
    u16* __restrict__ out) {
  int t = blockIdx.x * 256 + threadIdx.x;   // 4 * 16384
  int m = t >> 14, r = t & 16383;
  int n = r >> 7, k = r & 127;
  const float* src = (m == 0) ? W1 : (m == 1) ? W2 : epW1 + (size_t)(m - 2) * 16384;
  out[t] = f2bf(src[k * 128 + n]);
}

// ---- BN fold: alpha = g*rsqrt(v+eps), beta = (b - m)*alpha + be, per layer ----
// layout: [layer*256 + c] = alpha, [layer*256 + 128 + c] = beta
__global__ __launch_bounds__(256) void bnprep_k(
    const float* __restrict__ b1, const float* __restrict__ g1,
    const float* __restrict__ be1, const float* __restrict__ m1,
    const float* __restrict__ v1,
    const float* __restrict__ b2, const float* __restrict__ g2,
    const float* __restrict__ be2, const float* __restrict__ m2,
    const float* __restrict__ v2, float* __restrict__ out) {
  int t = threadIdx.x;
  int layer = t >> 7, c = t & 127;
  const float* bb = layer ? b2 : b1;
  const float* gg = layer ? g2 : g1;
  const float* ee = layer ? be2 : be1;
  const float* mm = layer ? m2 : m1;
  const float* vv = layer ? v2 : v1;
  float alpha = gg[c] * rsqrtf(vv[c] + BN_EPS);
  float beta = (bb[c] - mm[c]) * alpha + ee[c];
  out[layer * 256 + c] = alpha;
  out[layer * 256 + 128 + c] = beta;
}

// ---- MFMA GEMM: Y[M,128] = (X[M,128] @ W) (* dinv[row]); out bf16 or fp8 ----
template<bool BF16IN, bool SCALE, bool FP8OUT>
__global__ __launch_bounds__(256) void gemm_mfma_k(const void* __restrict__ Xv,
    const u16* __restrict__ Wt, const float* __restrict__ dinv,
    void* __restrict__ Yv, int M) {
  __shared__ u16 Xs[64][136];
  __shared__ u16 Ws[128][136];
  int tid = threadIdx.x;
  int row0 = blockIdx.x * 64;
  for (int i = tid; i < 2048; i += 256) {
    int n = i >> 4, c8 = i & 15;
    uint4 v = ((const uint4*)Wt)[i];
    *(uint4*)&Ws[n][c8 * 8] = v;
  }
  for (int i = tid; i < 1024; i += 256) {
    int r = i >> 4, c8 = i & 15;
    int gr = row0 + r;
    uint4 v = make_uint4(0u, 0u, 0u, 0u);
    if (gr < M) {
      if (BF16IN) {
        v = ((const uint4*)Xv)[(size_t)gr * 16 + c8];
      } else {
        const float* Xf = (const float*)Xv;
        float4 f0 = ((const float4*)Xf)[(size_t)gr * 32 + c8 * 2];
        float4 f1 = ((const float4*)Xf)[(size_t)gr * 32 + c8 * 2 + 1];
        v.x = packbf2(f0.x, f0.y); v.y = packbf2(f0.z, f0.w);
        v.z = packbf2(f1.x, f1.y); v.w = packbf2(f1.z, f1.w);
      }
    }
    *(uint4*)&Xs[r][c8 * 8] = v;
  }
  __syncthreads();
  int w = tid >> 6, l = tid & 63;
  int lr = l & 15, kq = l >> 4;
  bf16x8 a[4];
  #pragma unroll
  for (int kk = 0; kk < 4; ++kk)
    a[kk] = *(const bf16x8*)&Xs[w * 16 + lr][kk * 32 + kq * 8];
  float sc[4];
  #pragma unroll
  for (int r = 0; r < 4; ++r) {
    int grow = row0 + w * 16 + kq * 4 + r;
    sc[r] = (SCALE && grow < M) ? dinv[grow] : 1.f;
  }
  #pragma unroll
  for (int ct = 0; ct < 8; ++ct) {
    f32x4 c = {0.f, 0.f, 0.f, 0.f};
    #pragma unroll
    for (int kk = 0; kk < 4; ++kk) {
      bf16x8 b = *(const bf16x8*)&Ws[ct * 16 + lr][kk * 32 + kq * 8];
      c = __builtin_amdgcn_mfma_f32_16x16x32_bf16(a[kk], b, c, 0, 0, 0);
    }
    int n = ct * 16 + lr;
    #pragma unroll
    for (int r = 0; r < 4; ++r) {
      int grow = row0 + w * 16 + kq * 4 + r;
      if (grow < M) {
        float o = c[r];
        if (SCALE) o *= sc[r];
        if (FP8OUT) {
          ((u8*)Yv)[(size_t)grow * 128 + n] = f2fp8(o);
        } else {
          ((u16*)Yv)[(size_t)grow * 128 + n] = f2bf(o);
        }
      }
    }
  }
}

// ---- fused double GEMM (edge predictor): A out fp8 e4m3 (+bias), B out bf16 ----
__global__ __launch_bounds__(256) void gemm_mfma2_k(const u16* __restrict__ X,
    const u16* __restrict__ WtA, const u16* __restrict__ WtB,
    const float* __restrict__ bias, u8* __restrict__ YA8, u16* __restrict__ YB, int M) {
  __shared__ u16 Xs[64][136];
  __shared__ u16 Ws[128][136];
  int tid = threadIdx.x;
  int row0 = blockIdx.x * 64;
  for (int i = tid; i < 1024; i += 256) {
    int r = i >> 4, c8 = i & 15;
    int gr = row0 + r;
    uint4 v = make_uint4(0u, 0u, 0u, 0u);
    if (gr < M) v = ((const uint4*)X)[(size_t)gr * 16 + c8];
    *(uint4*)&Xs[r][c8 * 8] = v;
  }
  __syncthreads();
  int w = tid >> 6, l = tid & 63;
  int lr = l & 15, kq = l >> 4;
  bf16x8 a[4];
  #pragma unroll
  for (int kk = 0; kk < 4; ++kk)
    a[kk] = *(const bf16x8*)&Xs[w * 16 + lr][kk * 32 + kq * 8];

  for (int m = 0; m < 2; ++m) {
    const u16* Wt = m ? WtB : WtA;
    __syncthreads();
    for (int i = tid; i < 2048; i += 256) {
      int n = i >> 4, c8 = i & 15;
      uint4 v = ((const uint4*)Wt)[i];
      *(uint4*)&Ws[n][c8 * 8] = v;
    }
    __syncthreads();
    #pragma unroll
    for (int ct = 0; ct < 8; ++ct) {
      f32x4 c = {0.f, 0.f, 0.f, 0.f};
      #pragma unroll
      for (int kk = 0; kk < 4; ++kk) {
        bf16x8 b = *(const bf16x8*)&Ws[ct * 16 + lr][kk * 32 + kq * 8];
        c = __builtin_amdgcn_mfma_f32_16x16x32_bf16(a[kk], b, c, 0, 0, 0);
      }
      int n = ct * 16 + lr;
      if (m == 0) {
        float bv = bias[n];
        #pragma unroll
        for (int r = 0; r < 4; ++r) {
          int grow = row0 + w * 16 + kq * 4 + r;
          if (grow < M) YA8[(size_t)grow * 128 + n] = f2fp8(c[r] + bv);
        }
      } else {
        #pragma unroll
        for (int r = 0; r < 4; ++r) {
          int grow = row0 + w * 16 + kq * 4 + r;
          if (grow < M) YB[(size_t)grow * 128 + n] = f2bf(c[r]);
        }
      }
    }
  }
}

// --- agg: 16 lanes/node (4 nodes/wave); masked 8-deep gather; folded BN ---
__global__ __launch_bounds__(256) void agg_bn_relu_k(const u8* __restrict__ XW8,
    const int* __restrict__ rowptr, const int* __restrict__ csrS,
    const float* __restrict__ dinv, const float* __restrict__ ab,
    uint4* __restrict__ H4, int n) {
  int node = (blockIdx.x * 256 + threadIdx.x) >> 4;
  if (node >= n) return;
  int l16 = threadIdx.x & 15;
  int beg = rowptr[node], end = rowptr[node + 1];
  const uint2* X2 = (const uint2*)XW8;   // row = 16 uint2 (128B)
  float ac[8];
  #pragma unroll
  for (int j = 0; j < 8; ++j) ac[j] = 0.f;
  float f[8];
  for (int i = beg; i < end; i += 8) {
    int s[8];
    bool h[8];
    #pragma unroll
    for (int u = 0; u < 8; ++u) {
      int idx = i + u;
      h[u] = idx < end;
      s[u] = h[u] ? csrS[idx] : csrS[i];
    }
    uint2 p[8];
    #pragma unroll
    for (int u = 0; u < 8; ++u) p[u] = X2[(size_t)s[u] * 16 + l16];
    #pragma unroll
    for (int u = 0; u < 8; ++u) {
      if (h[u]) {
        unpack_fp8x4(p[u].x, f); unpack_fp8x4(p[u].y, f + 4);
        #pragma unroll
        for (int j = 0; j < 8; ++j) ac[j] += f[j];
      }
    }
  }
  {
    uint2 p = X2[(size_t)node * 16 + l16];
    unpack_fp8x4(p.x, f); unpack_fp8x4(p.y, f + 4);
    #pragma unroll
    for (int j = 0; j < 8; ++j) ac[j] += f[j];
  }
  float dn = dinv[node];
  int c = l16 * 8;
  float4 a0 = *(const float4*)&ab[c];
  float4 a1 = *(const float4*)&ab[c + 4];
  float4 t0 = *(const float4*)&ab[128 + c];
  float4 t1 = *(const float4*)&ab[128 + c + 4];
  float al[8] = {a0.x, a0.y, a0.z, a0.w, a1.x, a1.y, a1.z, a1.w};
  float bt[8] = {t0.x, t0.y, t0.z, t0.w, t1.x, t1.y, t1.z, t1.w};
  u32 out[4];
  #pragma unroll
  for (int j2 = 0; j2 < 4; ++j2) {
    float o0 = fmaxf(fmaf(ac[2*j2]     * dn, al[2*j2],     bt[2*j2]),     0.f);
    float o1 = fmaxf(fmaf(ac[2*j2 + 1] * dn, al[2*j2 + 1], bt[2*j2 + 1]), 0.f);
    out[j2] = packbf2(o0, o1);
  }
  H4[(size_t)node * 16 + l16] = make_uint4(out[0], out[1], out[2], out[3]);
}

// --- edge pass: node-major; B[d] bf16 in regs; gather A[s] fp8; 4 loads in flight ---
__global__ __launch_bounds__(256) void edge_pass_k(const u8* __restrict__ A8,
    const uint4* __restrict__ B4, const int* __restrict__ rowptr,
    const int* __restrict__ csrS, const float* __restrict__ w2,
    float* __restrict__ pout, int n) {
  int node = (blockIdx.x * 256 + threadIdx.x) >> 6;
  if (node >= n) return;
  int lane = threadIdx.x & 63;
  int sub = lane >> 4, l16 = lane & 15;
  int beg = rowptr[node], end = rowptr[node + 1];
  if (beg >= end) return;
  float bvals[8];
  unpack8(B4[(size_t)node * 16 + l16], bvals);
  int c = l16 * 8;
  float4 w0 = *(const float4*)&w2[c];
  float4 w1 = *(const float4*)&w2[c + 4];
  float wv[8] = {w0.x, w0.y, w0.z, w0.w, w1.x, w1.y, w1.z, w1.w};
  const uint2* A2 = (const uint2*)A8;
  for (int i = beg + sub; i < end; i += 16) {
    int i1 = i + 4, i2 = i + 8, i3 = i + 12;
    bool h1 = i1 < end, h2 = i2 < end, h3 = i3 < end;
    int s0 = csrS[i];
    int s1 = h1 ? csrS[i1] : s0;
    int s2 = h2 ? csrS[i2] : s0;
    int s3 = h3 ? csrS[i3] : s0;
    uint2 pa0 = A2[(size_t)s0 * 16 + l16];
    uint2 pa1 = A2[(size_t)s1 * 16 + l16];
    uint2 pa2 = A2[(size_t)s2 * 16 + l16];
    uint2 pa3 = A2[(size_t)s3 * 16 + l16];
    float f[8];
    float dot0 = 0.f, dot1 = 0.f, dot2 = 0.f, dot3 = 0.f;
    unpack_fp8x4(pa0.x, f); unpack_fp8x4(pa0.y, f + 4);
    #pragma unroll
    for (int j = 0; j < 8; ++j) dot0 = fmaf(fmaxf(f[j] + bvals[j], 0.f), wv[j], dot0);
    unpack_fp8x4(pa1.x, f); unpack_fp8x4(pa1.y, f + 4);
    #pragma unroll
    for (int j = 0; j < 8; ++j) dot1 = fmaf(fmaxf(f[j] + bvals[j], 0.f), wv[j], dot1);
    unpack_fp8x4(pa2.x, f); unpack_fp8x4(pa2.y, f + 4);
    #pragma unroll
    for (int j = 0; j < 8; ++j) dot2 = fmaf(fmaxf(f[j] + bvals[j], 0.f), wv[j], dot2);
    unpack_fp8x4(pa3.x, f); unpack_fp8x4(pa3.y, f + 4);
    #pragma unroll
    for (int j = 0; j < 8; ++j) dot3 = fmaf(fmaxf(f[j] + bvals[j], 0.f), wv[j], dot3);
    #pragma unroll
    for (int o = 1; o <= 8; o <<= 1) {
      dot0 += __shfl_xor(dot0, o);
      dot1 += __shfl_xor(dot1, o);
      dot2 += __shfl_xor(dot2, o);
      dot3 += __shfl_xor(dot3, o);
    }
    if (l16 == 0) {
      pout[i] = dot0;
      if (h1) pout[i1] = dot1;
      if (h2) pout[i2] = dot2;
      if (h3) pout[i3] = dot3;
    }
  }
}

// --- finalize: out[i] = sigmoid(pout[rowptr[dst[i]] + pintra[i]] + b2) ---
__global__ __launch_bounds__(256) void edge_fin_k(const float* __restrict__ pout,
    const int* __restrict__ dst, const int* __restrict__ pintra,
    const int* __restrict__ rowptr, const float* __restrict__ b2,
    float* __restrict__ out, int E) {
  int t = blockIdx.x * 256 + threadIdx.x;
  if (t >= E) return;
  int p = rowptr[dst[t]] + pintra[t];
  float z = pout[p] + b2[0];
  out[t] = 1.f / (1.f + expf(-z));
}

extern "C" void kernel_launch(void* const* d_in, const int* in_sizes, int n_in,
                              void* d_out, int out_size, void* d_ws, size_t ws_size,
                              hipStream_t stream) {
  const float* x    = (const float*)d_in[0];
  const int*   ei   = (const int*)d_in[1];
  const float* W1   = (const float*)d_in[2];
  const float* b1   = (const float*)d_in[3];
  const float* g1   = (const float*)d_in[4];
  const float* be1  = (const float*)d_in[5];
  const float* m1   = (const float*)d_in[6];
  const float* v1   = (const float*)d_in[7];
  const float* W2   = (const float*)d_in[8];
  const float* b2   = (const float*)d_in[9];
  const float* g2   = (const float*)d_in[10];
  const float* be2  = (const float*)d_in[11];
  const float* m2   = (const float*)d_in[12];
  const float* v2   = (const float*)d_in[13];
  const float* epW1 = (const float*)d_in[14];
  const float* epb1 = (const float*)d_in[15];
  const float* epW2 = (const float*)d_in[16];
  const float* epb2 = (const float*)d_in[17];

  int N = in_sizes[0] / 128;
  int E = in_sizes[1] / 2;
  const int* src = ei;
  const int* dst = ei + E;

  char* w = (char*)d_ws;
  size_t off = 0;
  auto carve = [&](size_t bytes) {
    void* p = w + off;
    off = (off + bytes + 255) & ~(size_t)255;
    return p;
  };
  u8*  bufX8 = (u8*)carve((size_t)N * 128);       // XW' fp8 (layer1/layer2 gathers)
  u16* bufH  = (u16*)carve((size_t)N * 128 * 2);  // h1 -> h2 (bf16)
  u16* bufB  = (u16*)carve((size_t)N * 128 * 2);  // B (bf16)
  u8*  bufA8 = (u8*)carve((size_t)N * 128);       // A (fp8 e4m3)
  int*   cnt   = (int*)carve((size_t)N * 4);
  int*   pintra= (int*)carve((size_t)E * 4);
  int*   rowptr= (int*)carve((size_t)(N + 1) * 4);
  float* dinv  = (float*)carve((size_t)N * 4);
  int*   csrS  = (int*)carve((size_t)E * 4);
  int*   bsum  = (int*)carve((size_t)1024 * 4);
  u16*   wsT   = (u16*)carve((size_t)4 * 16384 * 2);
  float* pout  = (float*)carve((size_t)E * 4);
  float* bnab  = (float*)carve((size_t)512 * 4);  // folded BN alpha/beta x2 layers
  (void)ws_size; (void)n_in; (void)out_size;

  int nb = (N + 255) / 256;
  int T = (E + 3) / 4;
  int tb = (T + 255) / 256;

  hipMemsetAsync(cnt, 0, (size_t)N * 4, stream);
  wconv_k<<<256, 256, 0, stream>>>(W1, W2, epW1, wsT);
  bnprep_k<<<1, 256, 0, stream>>>(b1, g1, be1, m1, v1, b2, g2, be2, m2, v2, bnab);
  count_pos_k<<<tb, 256, 0, stream>>>(dst, cnt, pintra, T, E);
  blocksum_k<<<nb, 256, 0, stream>>>(cnt, bsum, N);
  scan_bsum_k<<<1, 1024, 0, stream>>>(bsum, nb);
  scan_final_k<<<nb, 256, 0, stream>>>(cnt, bsum, rowptr, dinv, N);
  fill_csr_k<<<tb, 256, 0, stream>>>(src, dst, rowptr, pintra, csrS, T, E);

  int gb = (N + 63) / 64;
  int an = (N + 15) / 16;   // agg: 16 nodes per block (16 lanes/node)
  int ab = (N + 3) / 4;     // edge pass: wave per node
  const u16* WtW1 = wsT;
  const u16* WtW2 = wsT + 16384;
  const u16* WtA  = wsT + 2 * 16384;
  const u16* WtB  = wsT + 3 * 16384;

  // layer 1: XW' = dinv * (x @ W1) -> fp8
  gemm_mfma_k<false, true, true><<<gb, 256, 0, stream>>>(x, WtW1, dinv, bufX8, N);
  agg_bn_relu_k<<<an, 256, 0, stream>>>(bufX8, rowptr, csrS, dinv, bnab,
                                        (uint4*)bufH, N);
  // layer 2
  gemm_mfma_k<true, true, true><<<gb, 256, 0, stream>>>(bufH, WtW2, dinv, bufX8, N);
  agg_bn_relu_k<<<an, 256, 0, stream>>>(bufX8, rowptr, csrS, dinv, bnab + 256,
                                        (uint4*)bufH, N);
  // edge predictor: A (fp8, +epb1) and B (bf16), fused
  gemm_mfma2_k<<<gb, 256, 0, stream>>>(bufH, WtA, WtB, epb1, bufA8, bufB, N);
  // edge MLP partial dots (coalesced writes), then finalize with sigmoid
  edge_pass_k<<<ab, 256, 0, stream>>>(bufA8, (const uint4*)bufB, rowptr, csrS,
                                      epW2, pout, N);
  edge_fin_k<<<(E + 255) / 256, 256, 0, stream>>>(pout, dst, pintra, rowptr,
                                                  epb2, (float*)d_out, E);
}

// Round 15
// 211.068 us; speedup vs baseline: 2.0443x; 1.0125x over previous
//
#include <hip/hip_runtime.h>
#include <math.h>

#define BN_EPS 1e-5f

typedef unsigned short u16;
typedef unsigned int u32;
typedef unsigned char u8;
typedef __attribute__((ext_vector_type(8))) short bf16x8;
typedef __attribute__((ext_vector_type(4))) float f32x4;
typedef __attribute__((ext_vector_type(2))) float f32x2;

__device__ __forceinline__ u16 f2bf(float f) {
  u32 u = __float_as_uint(f);
  u32 r = (u + 0x7fffu + ((u >> 16) & 1u)) >> 16;   // RNE
  return (u16)r;
}
__device__ __forceinline__ u32 packbf2(float x, float y) {
  return (u32)f2bf(x) | ((u32)f2bf(y) << 16);
}
__device__ __forceinline__ float lo_bf(u32 p) { return __uint_as_float(p << 16); }
__device__ __forceinline__ float hi_bf(u32 p) { return __uint_as_float(p & 0xffff0000u); }

__device__ __forceinline__ void unpack8(uint4 p, float* f) {
  f[0] = lo_bf(p.x); f[1] = hi_bf(p.x);
  f[2] = lo_bf(p.y); f[3] = hi_bf(p.y);
  f[4] = lo_bf(p.z); f[5] = hi_bf(p.z);
  f[6] = lo_bf(p.w); f[7] = hi_bf(p.w);
}

// fp8 e4m3 x4 unpack, packed 2-at-a-time (v_cvt_pk_f32_fp8)
__device__ __forceinline__ void unpack_fp8x4(u32 p, float* f) {
  f32x2 lo = __builtin_amdgcn_cvt_pk_f32_fp8((int)p, false);
  f32x2 hi = __builtin_amdgcn_cvt_pk_f32_fp8((int)p, true);
  f[0] = lo.x; f[1] = lo.y; f[2] = hi.x; f[3] = hi.y;
}
__device__ __forceinline__ u8 f2fp8(float o) {
  u32 pk = __builtin_amdgcn_cvt_pk_fp8_f32(o, o, 0, false);
  return (u8)(pk & 0xffu);
}

// ---------------- workspace clear (replaces rocclr fillBuffer in-graph) ----------------
__global__ __launch_bounds__(256) void clear_k(int* __restrict__ p, int n) {
  int i = blockIdx.x * 256 + threadIdx.x;
  if (i < n) p[i] = 0;
}

// ---------------- CSR build ----------------
__global__ __launch_bounds__(256) void count_pos_k(const int* __restrict__ dst,
                                                   int* __restrict__ cnt,
                                                   int* __restrict__ pintra,
                                                   int T, int E) {
  int t = blockIdx.x * 256 + threadIdx.x;
  if (t >= T) return;
  int e0 = t, e1 = t + T, e2 = t + 2 * T, e3 = t + 3 * T;
  int d0 = (e0 < E) ? dst[e0] : -1;
  int d1 = (e1 < E) ? dst[e1] : -1;
  int d2 = (e2 < E) ? dst[e2] : -1;
  int d3 = (e3 < E) ? dst[e3] : -1;
  int p0 = (d0 >= 0) ? atomicAdd(&cnt[d0], 1) : 0;
  int p1 = (d1 >= 0) ? atomicAdd(&cnt[d1], 1) : 0;
  int p2 = (d2 >= 0) ? atomicAdd(&cnt[d2], 1) : 0;
  int p3 = (d3 >= 0) ? atomicAdd(&cnt[d3], 1) : 0;
  if (d0 >= 0) pintra[e0] = p0;
  if (d1 >= 0) pintra[e1] = p1;
  if (d2 >= 0) pintra[e2] = p2;
  if (d3 >= 0) pintra[e3] = p3;
}

__global__ __launch_bounds__(256) void blocksum_k(const int* __restrict__ cnt,
                                                  int* __restrict__ bsum, int n) {
  __shared__ int red[256];
  int tid = threadIdx.x;
  int i = blockIdx.x * 256 + tid;
  int v = (i < n) ? cnt[i] : 0;
  red[tid] = v;
  __syncthreads();
  for (int o = 128; o > 0; o >>= 1) {
    if (tid < o) red[tid] += red[tid + o];
    __syncthreads();
  }
  if (tid == 0) bsum[blockIdx.x] = red[0];
}

__global__ __launch_bounds__(1024) void scan_bsum_k(int* __restrict__ bsum, int nb) {
  __shared__ int part[1024];
  int tid = threadIdx.x;
  int v = (tid < nb) ? bsum[tid] : 0;
  part[tid] = v;
  __syncthreads();
  for (int o = 1; o < 1024; o <<= 1) {
    int t = (tid >= o) ? part[tid - o] : 0;
    __syncthreads();
    part[tid] += t;
    __syncthreads();
  }
  if (tid < nb) bsum[tid] = part[tid] - v;   // exclusive
}

__global__ __launch_bounds__(256) void scan_final_k(const int* __restrict__ cnt,
                                                    const int* __restrict__ bsum,
                                                    int* __restrict__ rowptr,
                                                    float* __restrict__ dinv, int n) {
  __shared__ int part[256];
  int tid = threadIdx.x;
  int i = blockIdx.x * 256 + tid;
  int v = (i < n) ? cnt[i] : 0;
  part[tid] = v;
  __syncthreads();
  for (int o = 1; o < 256; o <<= 1) {
    int t = (tid >= o) ? part[tid - o] : 0;
    __syncthreads();
    part[tid] += t;
    __syncthreads();
  }
  if (i < n) {
    int excl = part[tid] - v + bsum[blockIdx.x];
    rowptr[i] = excl;
    dinv[i] = rsqrtf((float)(v + 1));   // deg = in-degree + self-loop
    if (i == n - 1) rowptr[n] = excl + v;
  }
}

// scatter 4B src per edge; eid recoverable as rowptr[dst[e]] + pintra[e]
__global__ __launch_bounds__(256) void fill_csr_k(const int* __restrict__ src,
                                                  const int* __restrict__ dst,
                                                  const int* __restrict__ rowptr,
                                                  const int* __restrict__ pintra,
                                                  int* __restrict__ csrS, int T, int E) {
  int t = blockIdx.x * 256 + threadIdx.x;
  if (t >= T) return;
  #pragma unroll
  for (int u = 0; u < 4; ++u) {
    int e = t + u * T;
    if (e < E) {
      int d = dst[e];
      int p = rowptr[d] + pintra[e];
      csrS[p] = src[e];
    }
  }
}

// ---- prep: weights fp32->transposed bf16 (blocks 0..255) + BN fold (block 256) ----
__global__ __launch_bounds__(256) void prep_k(const float* __restrict__ W1,
    const float* __restrict__ W2, const float* __restrict__ epW1,
    const float* __restrict__ b1, const float* __restrict__ g1,
    const float* __restrict__ be1, const float* __restrict__ m1,
    const float* __restrict__ v1,
    const float* __restrict__ b2, const float* __restrict__ g2,
    const float* __restrict__ be2, const float* __restrict__ m2,
    const float* __restrict__ v2,
    u16* __restrict__ wout, float* __restrict__ bnout) {
  if (blockIdx.x < 256) {
    int t = blockIdx.x * 256 + threadIdx.x;   // 4 * 16384
    int m = t >> 14, r = t & 16383;
    int n = r >> 7, k = r & 127;
    const float* src = (m == 0) ? W1 : (m == 1) ? W2 : epW1 + (size_t)(m - 2) * 16384;
    wout[t] = f2bf(src[k * 128 + n]);
  } else {
    int t = threadIdx.x;
    int layer = t >> 7, c = t & 127;
    const float* bb = layer ? b2 : b1;
    const float* gg = layer ? g2 : g1;
    const float* ee = layer ? be2 : be1;
    const float* mm = layer ? m2 : m1;
    const float* vv = layer ? v2 : v1;
    float alpha = gg[c] * rsqrtf(vv[c] + BN_EPS);
    float beta = (bb[c] - mm[c]) * alpha + ee[c];
    bnout[layer * 256 + c] = alpha;
    bnout[layer * 256 + 128 + c] = beta;
  }
}

// ---- MFMA GEMM: Y[M,128] = (X[M,128] @ W) (* dinv[row]); out bf16 or fp8 ----
template<bool BF16IN, bool SCALE, bool FP8OUT>
__global__ __launch_bounds__(256) void gemm_mfma_k(const void* __restrict__ Xv,
    const u16* __restrict__ Wt, const float* __restrict__ dinv,
    void* __restrict__ Yv, int M) {
  __shared__ u16 Xs[64][136];
  __shared__ u16 Ws[128][136];
  int tid = threadIdx.x;
  int row0 = blockIdx.x * 64;
  for (int i = tid; i < 2048; i += 256) {
    int n = i >> 4, c8 = i & 15;
    uint4 v = ((const uint4*)Wt)[i];
    *(uint4*)&Ws[n][c8 * 8] = v;
  }
  for (int i = tid; i < 1024; i += 256) {
    int r = i >> 4, c8 = i & 15;
    int gr = row0 + r;
    uint4 v = make_uint4(0u, 0u, 0u, 0u);
    if (gr < M) {
      if (BF16IN) {
        v = ((const uint4*)Xv)[(size_t)gr * 16 + c8];
      } else {
        const float* Xf = (const float*)Xv;
        float4 f0 = ((const float4*)Xf)[(size_t)gr * 32 + c8 * 2];
        float4 f1 = ((const float4*)Xf)[(size_t)gr * 32 + c8 * 2 + 1];
        v.x = packbf2(f0.x, f0.y); v.y = packbf2(f0.z, f0.w);
        v.z = packbf2(f1.x, f1.y); v.w = packbf2(f1.z, f1.w);
      }
    }
    *(uint4*)&Xs[r][c8 * 8] = v;
  }
  __syncthreads();
  int w = tid >> 6, l = tid & 63;
  int lr = l & 15, kq = l >> 4;
  bf16x8 a[4];
  #pragma unroll
  for (int kk = 0; kk < 4; ++kk)
    a[kk] = *(const bf16x8*)&Xs[w * 16 + lr][kk * 32 + kq * 8];
  float sc[4];
  #pragma unroll
  for (int r = 0; r < 4; ++r) {
    int grow = row0 + w * 16 + kq * 4 + r;
    sc[r] = (SCALE && grow < M) ? dinv[grow] : 1.f;
  }
  #pragma unroll
  for (int ct = 0; ct < 8; ++ct) {
    f32x4 c = {0.f, 0.f, 0.f, 0.f};
    #pragma unroll
    for (int kk = 0; kk < 4; ++kk) {
      bf16x8 b = *(const bf16x8*)&Ws[ct * 16 + lr][kk * 32 + kq * 8];
      c = __builtin_amdgcn_mfma_f32_16x16x32_bf16(a[kk], b, c, 0, 0, 0);
    }
    int n = ct * 16 + lr;
    #pragma unroll
    for (int r = 0; r < 4; ++r) {
      int grow = row0 + w * 16 + kq * 4 + r;
      if (grow < M) {
        float o = c[r];
        if (SCALE) o *= sc[r];
        if (FP8OUT) {
          ((u8*)Yv)[(size_t)grow * 128 + n] = f2fp8(o);
        } else {
          ((u16*)Yv)[(size_t)grow * 128 + n] = f2bf(o);
        }
      }
    }
  }
}

// ---- fused double GEMM (edge predictor): A out fp8 e4m3 (+bias), B out bf16 ----
__global__ __launch_bounds__(256) void gemm_mfma2_k(const u16* __restrict__ X,
    const u16* __restrict__ WtA, const u16* __restrict__ WtB,
    const float* __restrict__ bias, u8* __restrict__ YA8, u16* __restrict__ YB, int M) {
  __shared__ u16 Xs[64][136];
  __shared__ u16 Ws[128][136];
  int tid = threadIdx.x;
  int row0 = blockIdx.x * 64;
  for (int i = tid; i < 1024; i += 256) {
    int r = i >> 4, c8 = i & 15;
    int gr = row0 + r;
    uint4 v = make_uint4(0u, 0u, 0u, 0u);
    if (gr < M) v = ((const uint4*)X)[(size_t)gr * 16 + c8];
    *(uint4*)&Xs[r][c8 * 8] = v;
  }
  __syncthreads();
  int w = tid >> 6, l = tid & 63;
  int lr = l & 15, kq = l >> 4;
  bf16x8 a[4];
  #pragma unroll
  for (int kk = 0; kk < 4; ++kk)
    a[kk] = *(const bf16x8*)&Xs[w * 16 + lr][kk * 32 + kq * 8];

  for (int m = 0; m < 2; ++m) {
    const u16* Wt = m ? WtB : WtA;
    __syncthreads();
    for (int i = tid; i < 2048; i += 256) {
      int n = i >> 4, c8 = i & 15;
      uint4 v = ((const uint4*)Wt)[i];
      *(uint4*)&Ws[n][c8 * 8] = v;
    }
    __syncthreads();
    #pragma unroll
    for (int ct = 0; ct < 8; ++ct) {
      f32x4 c = {0.f, 0.f, 0.f, 0.f};
      #pragma unroll
      for (int kk = 0; kk < 4; ++kk) {
        bf16x8 b = *(const bf16x8*)&Ws[ct * 16 + lr][kk * 32 + kq * 8];
        c = __builtin_amdgcn_mfma_f32_16x16x32_bf16(a[kk], b, c, 0, 0, 0);
      }
      int n = ct * 16 + lr;
      if (m == 0) {
        float bv = bias[n];
        #pragma unroll
        for (int r = 0; r < 4; ++r) {
          int grow = row0 + w * 16 + kq * 4 + r;
          if (grow < M) YA8[(size_t)grow * 128 + n] = f2fp8(c[r] + bv);
        }
      } else {
        #pragma unroll
        for (int r = 0; r < 4; ++r) {
          int grow = row0 + w * 16 + kq * 4 + r;
          if (grow < M) YB[(size_t)grow * 128 + n] = f2bf(c[r]);
        }
      }
    }
  }
}

// --- agg: 16 lanes/node (4 nodes/wave); masked 8-deep gather; folded BN ---
__global__ __launch_bounds__(256) void agg_bn_relu_k(const u8* __restrict__ XW8,
    const int* __restrict__ rowptr, const int* __restrict__ csrS,
    const float* __restrict__ dinv, const float* __restrict__ ab,
    uint4* __restrict__ H4, int n) {
  int node = (blockIdx.x * 256 + threadIdx.x) >> 4;
  if (node >= n) return;
  int l16 = threadIdx.x & 15;
  int beg = rowptr[node], end = rowptr[node + 1];
  const uint2* X2 = (const uint2*)XW8;   // row = 16 uint2 (128B)
  float ac[8];
  #pragma unroll
  for (int j = 0; j < 8; ++j) ac[j] = 0.f;
  float f[8];
  for (int i = beg; i < end; i += 8) {
    int s[8];
    bool h[8];
    #pragma unroll
    for (int u = 0; u < 8; ++u) {
      int idx = i + u;
      h[u] = idx < end;
      s[u] = h[u] ? csrS[idx] : csrS[i];
    }
    uint2 p[8];
    #pragma unroll
    for (int u = 0; u < 8; ++u) p[u] = X2[(size_t)s[u] * 16 + l16];
    #pragma unroll
    for (int u = 0; u < 8; ++u) {
      if (h[u]) {
        unpack_fp8x4(p[u].x, f); unpack_fp8x4(p[u].y, f + 4);
        #pragma unroll
        for (int j = 0; j < 8; ++j) ac[j] += f[j];
      }
    }
  }
  {
    uint2 p = X2[(size_t)node * 16 + l16];
    unpack_fp8x4(p.x, f); unpack_fp8x4(p.y, f + 4);
    #pragma unroll
    for (int j = 0; j < 8; ++j) ac[j] += f[j];
  }
  float dn = dinv[node];
  int c = l16 * 8;
  float4 a0 = *(const float4*)&ab[c];
  float4 a1 = *(const float4*)&ab[c + 4];
  float4 t0 = *(const float4*)&ab[128 + c];
  float4 t1 = *(const float4*)&ab[128 + c + 4];
  float al[8] = {a0.x, a0.y, a0.z, a0.w, a1.x, a1.y, a1.z, a1.w};
  float bt[8] = {t0.x, t0.y, t0.z, t0.w, t1.x, t1.y, t1.z, t1.w};
  u32 out[4];
  #pragma unroll
  for (int j2 = 0; j2 < 4; ++j2) {
    float o0 = fmaxf(fmaf(ac[2*j2]     * dn, al[2*j2],     bt[2*j2]),     0.f);
    float o1 = fmaxf(fmaf(ac[2*j2 + 1] * dn, al[2*j2 + 1], bt[2*j2 + 1]), 0.f);
    out[j2] = packbf2(o0, o1);
  }
  H4[(size_t)node * 16 + l16] = make_uint4(out[0], out[1], out[2], out[3]);
}

// --- edge pass: node-major; B[d] bf16 in regs; gather A[s] fp8; 4 loads in flight ---
__global__ __launch_bounds__(256) void edge_pass_k(const u8* __restrict__ A8,
    const uint4* __restrict__ B4, const int* __restrict__ rowptr,
    const int* __restrict__ csrS, const float* __restrict__ w2,
    float* __restrict__ pout, int n) {
  int node = (blockIdx.x * 256 + threadIdx.x) >> 6;
  if (node >= n) return;
  int lane = threadIdx.x & 63;
  int sub = lane >> 4, l16 = lane & 15;
  int beg = rowptr[node], end = rowptr[node + 1];
  if (beg >= end) return;
  float bvals[8];
  unpack8(B4[(size_t)node * 16 + l16], bvals);
  int c = l16 * 8;
  float4 w0 = *(const float4*)&w2[c];
  float4 w1 = *(const float4*)&w2[c + 4];
  float wv[8] = {w0.x, w0.y, w0.z, w0.w, w1.x, w1.y, w1.z, w1.w};
  const uint2* A2 = (const uint2*)A8;
  for (int i = beg + sub; i < end; i += 16) {
    int i1 = i + 4, i2 = i + 8, i3 = i + 12;
    bool h1 = i1 < end, h2 = i2 < end, h3 = i3 < end;
    int s0 = csrS[i];
    int s1 = h1 ? csrS[i1] : s0;
    int s2 = h2 ? csrS[i2] : s0;
    int s3 = h3 ? csrS[i3] : s0;
    uint2 pa0 = A2[(size_t)s0 * 16 + l16];
    uint2 pa1 = A2[(size_t)s1 * 16 + l16];
    uint2 pa2 = A2[(size_t)s2 * 16 + l16];
    uint2 pa3 = A2[(size_t)s3 * 16 + l16];
    float f[8];
    float dot0 = 0.f, dot1 = 0.f, dot2 = 0.f, dot3 = 0.f;
    unpack_fp8x4(pa0.x, f); unpack_fp8x4(pa0.y, f + 4);
    #pragma unroll
    for (int j = 0; j < 8; ++j) dot0 = fmaf(fmaxf(f[j] + bvals[j], 0.f), wv[j], dot0);
    unpack_fp8x4(pa1.x, f); unpack_fp8x4(pa1.y, f + 4);
    #pragma unroll
    for (int j = 0; j < 8; ++j) dot1 = fmaf(fmaxf(f[j] + bvals[j], 0.f), wv[j], dot1);
    unpack_fp8x4(pa2.x, f); unpack_fp8x4(pa2.y, f + 4);
    #pragma unroll
    for (int j = 0; j < 8; ++j) dot2 = fmaf(fmaxf(f[j] + bvals[j], 0.f), wv[j], dot2);
    unpack_fp8x4(pa3.x, f); unpack_fp8x4(pa3.y, f + 4);
    #pragma unroll
    for (int j = 0; j < 8; ++j) dot3 = fmaf(fmaxf(f[j] + bvals[j], 0.f), wv[j], dot3);
    #pragma unroll
    for (int o = 1; o <= 8; o <<= 1) {
      dot0 += __shfl_xor(dot0, o);
      dot1 += __shfl_xor(dot1, o);
      dot2 += __shfl_xor(dot2, o);
      dot3 += __shfl_xor(dot3, o);
    }
    if (l16 == 0) {
      pout[i] = dot0;
      if (h1) pout[i1] = dot1;
      if (h2) pout[i2] = dot2;
      if (h3) pout[i3] = dot3;
    }
  }
}

// --- finalize: out[i] = sigmoid(pout[rowptr[dst[i]] + pintra[i]] + b2) ---
__global__ __launch_bounds__(256) void edge_fin_k(const float* __restrict__ pout,
    const int* __restrict__ dst, const int* __restrict__ pintra,
    const int* __restrict__ rowptr, const float* __restrict__ b2,
    float* __restrict__ out, int E) {
  int t = blockIdx.x * 256 + threadIdx.x;
  if (t >= E) return;
  int p = rowptr[dst[t]] + pintra[t];
  float z = pout[p] + b2[0];
  out[t] = 1.f / (1.f + expf(-z));
}

extern "C" void kernel_launch(void* const* d_in, const int* in_sizes, int n_in,
                              void* d_out, int out_size, void* d_ws, size_t ws_size,
                              hipStream_t stream) {
  const float* x    = (const float*)d_in[0];
  const int*   ei   = (const int*)d_in[1];
  const float* W1   = (const float*)d_in[2];
  const float* b1   = (const float*)d_in[3];
  const float* g1   = (const float*)d_in[4];
  const float* be1  = (const float*)d_in[5];
  const float* m1   = (const float*)d_in[6];
  const float* v1   = (const float*)d_in[7];
  const float* W2   = (const float*)d_in[8];
  const float* b2   = (const float*)d_in[9];
  const float* g2   = (const float*)d_in[10];
  const float* be2  = (const float*)d_in[11];
  const float* m2   = (const float*)d_in[12];
  const float* v2   = (const float*)d_in[13];
  const float* epW1 = (const float*)d_in[14];
  const float* epb1 = (const float*)d_in[15];
  const float* epW2 = (const float*)d_in[16];
  const float* epb2 = (const float*)d_in[17];

  int N = in_sizes[0] / 128;
  int E = in_sizes[1] / 2;
  const int* src = ei;
  const int* dst = ei + E;

  char* w = (char*)d_ws;
  size_t off = 0;
  auto carve = [&](size_t bytes) {
    void* p = w + off;
    off = (off + bytes + 255) & ~(size_t)255;
    return p;
  };
  u8*  bufX8 = (u8*)carve((size_t)N * 128);       // XW' fp8 (layer1/layer2 gathers)
  u16* bufH  = (u16*)carve((size_t)N * 128 * 2);  // h1 -> h2 (bf16)
  u16* bufB  = (u16*)carve((size_t)N * 128 * 2);  // B (bf16)
  u8*  bufA8 = (u8*)carve((size_t)N * 128);       // A (fp8 e4m3)
  int*   cnt   = (int*)carve((size_t)N * 4);
  int*   pintra= (int*)carve((size_t)E * 4);
  int*   rowptr= (int*)carve((size_t)(N + 1) * 4);
  float* dinv  = (float*)carve((size_t)N * 4);
  int*   csrS  = (int*)carve((size_t)E * 4);
  int*   bsum  = (int*)carve((size_t)1024 * 4);
  u16*   wsT   = (u16*)carve((size_t)4 * 16384 * 2);
  float* pout  = (float*)carve((size_t)E * 4);
  float* bnab  = (float*)carve((size_t)512 * 4);  // folded BN alpha/beta x2 layers
  (void)ws_size; (void)n_in; (void)out_size;

  int nb = (N + 255) / 256;
  int T = (E + 3) / 4;
  int tb = (T + 255) / 256;

  clear_k<<<nb, 256, 0, stream>>>(cnt, N);
  prep_k<<<257, 256, 0, stream>>>(W1, W2, epW1, b1, g1, be1, m1, v1,
                                  b2, g2, be2, m2, v2, wsT, bnab);
  count_pos_k<<<tb, 256, 0, stream>>>(dst, cnt, pintra, T, E);
  blocksum_k<<<nb, 256, 0, stream>>>(cnt, bsum, N);
  scan_bsum_k<<<1, 1024, 0, stream>>>(bsum, nb);
  scan_final_k<<<nb, 256, 0, stream>>>(cnt, bsum, rowptr, dinv, N);
  fill_csr_k<<<tb, 256, 0, stream>>>(src, dst, rowptr, pintra, csrS, T, E);

  int gb = (N + 63) / 64;
  int an = (N + 15) / 16;   // agg: 16 nodes per block (16 lanes/node)
  int ab = (N + 3) / 4;     // edge pass: wave per node
  const u16* WtW1 = wsT;
  const u16* WtW2 = wsT + 16384;
  const u16* WtA  = wsT + 2 * 16384;
  const u16* WtB  = wsT + 3 * 16384;

  // layer 1: XW' = dinv * (x @ W1) -> fp8
  gemm_mfma_k<false, true, true><<<gb, 256, 0, stream>>>(x, WtW1, dinv, bufX8, N);
  agg_bn_relu_k<<<an, 256, 0, stream>>>(bufX8, rowptr, csrS, dinv, bnab,
                                        (uint4*)bufH, N);
  // layer 2
  gemm_mfma_k<true, true, true><<<gb, 256, 0, stream>>>(bufH, WtW2, dinv, bufX8, N);
  agg_bn_relu_k<<<an, 256, 0, stream>>>(bufX8, rowptr, csrS, dinv, bnab + 256,
                                        (uint4*)bufH, N);
  // edge predictor: A (fp8, +epb1) and B (bf16), fused
  gemm_mfma2_k<<<gb, 256, 0, stream>>>(bufH, WtA, WtB, epb1, bufA8, bufB, N);
  // edge MLP partial dots (coalesced writes), then finalize with sigmoid
  edge_pass_k<<<ab, 256, 0, stream>>>(bufA8, (const uint4*)bufB, rowptr, csrS,
                                      epW2, pout, N);
  edge_fin_k<<<(E + 255) / 256, 256, 0, stream>>>(pout, dst, pintra, rowptr,
                                                  epb2, (float*)d_out, E);
}